// Round 2
// baseline (797.676 us; speedup 1.0000x reference)
//
#include <hip/hip_runtime.h>
#include <hip/hip_bf16.h>
#include <math.h>

typedef __attribute__((ext_vector_type(8))) short short8;
typedef __attribute__((ext_vector_type(4))) float floatx4;
typedef __attribute__((ext_vector_type(4))) unsigned int uintx4;

__device__ __forceinline__ unsigned short f2bf(float f) {
    unsigned int u = __float_as_uint(f);
    unsigned int r = (u + 0x7fffu + ((u >> 16) & 1u)) >> 16;
    return (unsigned short)r;
}

__device__ __forceinline__ floatx4 mfma16(short8 a, short8 b, floatx4 c) {
    return __builtin_amdgcn_mfma_f32_16x16x32_bf16(a, b, c, 0, 0, 0);
}

// ---------------- Phase A: weight reductions / quantization / tables ----------------

__global__ void k_sumabs(const float* __restrict__ W1, const float* __restrict__ W2,
                         float* s1sum, float* s2sum) {
    int b = blockIdx.x;
    const float* W = (b < 16) ? (W1 + (long)b * 65536) : (W2 + (long)(b - 16) * 65536);
    float s = 0.f;
    for (int i = threadIdx.x; i < 65536; i += 256) s += fabsf(W[i]);
    __shared__ float red[256];
    red[threadIdx.x] = s; __syncthreads();
    for (int st = 128; st > 0; st >>= 1) {
        if (threadIdx.x < st) red[threadIdx.x] += red[threadIdx.x + st];
        __syncthreads();
    }
    if (threadIdx.x == 0) { if (b < 16) s1sum[b] = red[0]; else s2sum[b - 16] = red[0]; }
}

__global__ void k_quant(const float* __restrict__ W1, const float* __restrict__ W2,
                        const float* __restrict__ s1sum, const float* __restrict__ s2sum,
                        unsigned short* __restrict__ W1qT, unsigned short* __restrict__ W2qT,
                        float* ternsum) {
    long e = (long)blockIdx.x * 256 + threadIdx.x;
    bool isW1 = e < 1048576;
    long el = isW1 ? e : e - 1048576;
    int t = (int)(el >> 16); int loc = (int)(el & 65535);
    float s = (isW1 ? s1sum[t] : s2sum[t]) * (1.0f / 65536.0f);
    float w = (isW1 ? W1 : W2)[el];
    float q = (fabsf(w) > 0.7f * s) ? (w > 0.f ? s : -s) : 0.0f;
    float d = fabsf(w - q);
    if (isW1) { int k = loc >> 9, n = loc & 511; W1qT[(long)t * 65536 + n * 128 + k] = f2bf(q); }
    else      { int kf = loc >> 7, dd = loc & 127; W2qT[(long)t * 65536 + dd * 512 + kf] = f2bf(q); }
    __shared__ float red[256];
    red[threadIdx.x] = d; __syncthreads();
    for (int st = 128; st > 0; st >>= 1) {
        if (threadIdx.x < st) red[threadIdx.x] += red[threadIdx.x + st];
        __syncthreads();
    }
    if (threadIdx.x == 0) atomicAdd(ternsum, red[0]);
}

__global__ void k_tables(const float* __restrict__ op_embed, const float* __restrict__ W_in,
                         const float* __restrict__ b_in, const float* __restrict__ Wh1,
                         float* embW, float* Ta, float* Tb, float* Tc,
                         unsigned short* Wh1T) {
    int i = blockIdx.x * 256 + threadIdx.x;
    if (i < 1024) {                      // embW' = op_embed@W_in[0:32] + b_in
        int op = i >> 7, j = i & 127;
        float s = b_in[j];
        #pragma unroll
        for (int k = 0; k < 32; k++) s += op_embed[op * 32 + k] * W_in[k * 128 + j];
        embW[i] = s;
    } else if (i < 1024 + 32768) {       // Ta[a] = bits(a)@W_in[32:40]
        int r = i - 1024; int a = r >> 7, j = r & 127;
        float s = 0.f;
        #pragma unroll
        for (int bit = 0; bit < 8; bit++) if ((a >> bit) & 1) s += W_in[(32 + bit) * 128 + j];
        Ta[r] = s;
    } else if (i < 1024 + 65536) {       // Tb[b] = bits(b)@W_in[40:48]
        int r = i - 33792; int b = r >> 7, j = r & 127;
        float s = 0.f;
        #pragma unroll
        for (int bit = 0; bit < 8; bit++) if ((b >> bit) & 1) s += W_in[(40 + bit) * 128 + j];
        Tb[r] = s;
    } else if (i < 66560 + 128) {        // Tc = W_in row 48
        int j = i - 66560; Tc[j] = W_in[48 * 128 + j];
    } else if (i < 66688 + 8192) {       // Wh1T[h][k] = Wh1[k][h] (bf16)
        int r = i - 66688; int h = r >> 7, k = r & 127;
        Wh1T[r] = f2bf(Wh1[k * 64 + h]);
    }
}

__global__ void k_tablesR(const float* __restrict__ embW, const float* __restrict__ Ta,
                          const float* __restrict__ Tb, const float* __restrict__ Tc,
                          const float* __restrict__ Wr,
                          float* embWr, float* TaR, float* TbR, float* TcR) {
    int i = blockIdx.x * 256 + threadIdx.x;
    int row = i >> 4, t = i & 15;
    const float* src; float* dst;
    if (row < 8)        { src = embW + row * 128;        dst = embWr + i; }
    else if (row < 264) { src = Ta + (row - 8) * 128;    dst = TaR + (row - 8) * 16 + t; }
    else if (row < 520) { src = Tb + (row - 264) * 128;  dst = TbR + (row - 264) * 16 + t; }
    else if (row == 520){ src = Tc;                      dst = TcR + t; }
    else return;
    float s = 0.f;
    for (int j = 0; j < 128; j++) s += src[j] * Wr[j * 16 + t];
    *dst = s;
}

// ---------------- Phase B: router + x + histogram ----------------

__global__ void k_front(const int* __restrict__ op_idx, const int* __restrict__ a_in,
                        const int* __restrict__ b_in_i, const int* __restrict__ c_in,
                        const float* __restrict__ embW, const float* __restrict__ Ta,
                        const float* __restrict__ Tb, const float* __restrict__ Tc,
                        const float* __restrict__ embWr, const float* __restrict__ TaR,
                        const float* __restrict__ TbR, const float* __restrict__ TcR,
                        unsigned short* __restrict__ xq, float* __restrict__ gate_out,
                        float* psum, int* cnt, float* __restrict__ d_idx) {
    __shared__ float lp[16]; __shared__ int lc[16];
    if (threadIdx.x < 16) { lp[threadIdx.x] = 0.f; lc[threadIdx.x] = 0; }
    __syncthreads();

    int tok = blockIdx.x * 256 + threadIdx.x;
    int op = op_idx[tok], a = a_in[tok], b = b_in_i[tok], c = c_in[tok];
    float cf = (float)c;

    // logits via decomposed tables (fp32)
    float l[16];
    const floatx4* e4 = (const floatx4*)(embWr + op * 16);
    const floatx4* a4 = (const floatx4*)(TaR + a * 16);
    const floatx4* b4 = (const floatx4*)(TbR + b * 16);
    const floatx4* c4 = (const floatx4*)TcR;
    #pragma unroll
    for (int q = 0; q < 4; q++) {
        floatx4 v = e4[q] + a4[q] + b4[q] + cf * c4[q];
        l[q * 4 + 0] = v[0]; l[q * 4 + 1] = v[1]; l[q * 4 + 2] = v[2]; l[q * 4 + 3] = v[3];
    }
    float best = l[0]; int bi = 0;
    #pragma unroll
    for (int t = 1; t < 16; t++) if (l[t] > best) { best = l[t]; bi = t; }
    float p[16]; float ssum = 0.f;
    #pragma unroll
    for (int t = 0; t < 16; t++) { p[t] = __expf(l[t] - best); ssum += p[t]; }
    float g = 1.0f / ssum;                       // = max prob
    gate_out[tok] = g;
    d_idx[tok] = (float)bi;

    // x (bf16) via decomposed tables
    const floatx4* E  = (const floatx4*)(embW + op * 128);
    const floatx4* A4 = (const floatx4*)(Ta + a * 128);
    const floatx4* B4 = (const floatx4*)(Tb + b * 128);
    const floatx4* C4 = (const floatx4*)Tc;
    uintx4* xrow = (uintx4*)(xq + (long)tok * 128);
    #pragma unroll
    for (int q8 = 0; q8 < 16; q8++) {
        floatx4 v0 = E[2 * q8] + A4[2 * q8] + B4[2 * q8] + cf * C4[2 * q8];
        floatx4 v1 = E[2 * q8 + 1] + A4[2 * q8 + 1] + B4[2 * q8 + 1] + cf * C4[2 * q8 + 1];
        uintx4 o;
        o[0] = (unsigned)f2bf(v0[0]) | ((unsigned)f2bf(v0[1]) << 16);
        o[1] = (unsigned)f2bf(v0[2]) | ((unsigned)f2bf(v0[3]) << 16);
        o[2] = (unsigned)f2bf(v1[0]) | ((unsigned)f2bf(v1[1]) << 16);
        o[3] = (unsigned)f2bf(v1[2]) | ((unsigned)f2bf(v1[3]) << 16);
        xrow[q8] = o;
    }

    #pragma unroll
    for (int t = 0; t < 16; t++) atomicAdd(&lp[t], p[t] * g);
    atomicAdd(&lc[bi], 1);
    __syncthreads();
    if (threadIdx.x < 16) {
        atomicAdd(&cnt[threadIdx.x], lc[threadIdx.x]);
        atomicAdd(&psum[threadIdx.x], lp[threadIdx.x]);
    }
}

// ---------------- prefix + aux (single thread) ----------------

__global__ void k_prefix_aux(const int* __restrict__ cnt, const float* __restrict__ psum,
                             const float* __restrict__ ternsum,
                             int* offsets, int* chunkpre, float* d_aux, float Bf) {
    if (threadIdx.x == 0 && blockIdx.x == 0) {
        int off = 0, coff = 0;
        for (int t = 0; t < 16; t++) {
            offsets[t] = off; chunkpre[t] = coff;
            off += cnt[t]; coff += (cnt[t] + 63) >> 6;
        }
        offsets[16] = off; chunkpre[16] = coff;
        float tern = ternsum[0] * (1.0f / 1048576.0f);
        float sp = 0.f; float cp[4] = {0.f, 0.f, 0.f, 0.f};
        for (int t = 0; t < 16; t++) {
            float frac = (float)cnt[t] / Bf, mp = psum[t] / Bf;
            sp += frac * mp; cp[t >> 2] += mp;
        }
        float dv = 0.f;
        for (int cc = 0; cc < 4; cc++) dv += cp[cc] * logf(cp[cc] + 1e-9f);
        d_aux[0] = 0.01f * tern + 0.005f * (16.0f * sp) + 0.01f * dv;
    }
}

// ---------------- scatter into per-tile buckets ----------------

__global__ void k_scatter(const float* __restrict__ d_idx, const int* __restrict__ offsets,
                          int* fill, int* __restrict__ bucket) {
    __shared__ int lc[16], lbase[16];
    if (threadIdx.x < 16) lc[threadIdx.x] = 0;
    __syncthreads();
    int tok = blockIdx.x * 256 + threadIdx.x;
    int t = (int)d_idx[tok];
    int lpos = atomicAdd(&lc[t], 1);
    __syncthreads();
    if (threadIdx.x < 16) lbase[threadIdx.x] = atomicAdd(&fill[threadIdx.x], lc[threadIdx.x]);
    __syncthreads();
    bucket[offsets[t] + lbase[t] + lpos] = tok;
}

// ---------------- Phase C: MoE FFN + head (MFMA) ----------------

__global__ __launch_bounds__(256) void k_ffn(
    const unsigned short* __restrict__ xq, const float* __restrict__ gate,
    const int* __restrict__ bucket, const int* __restrict__ cnt,
    const int* __restrict__ offsets, const int* __restrict__ chunkpre,
    const unsigned short* __restrict__ W1qT, const unsigned short* __restrict__ W2qT,
    const unsigned short* __restrict__ Wh1T, const float* __restrict__ Wh2,
    const float* __restrict__ bh1, const float* __restrict__ bh2,
    float* __restrict__ result) {

    extern __shared__ __align__(16) unsigned char smem[];
    unsigned short* Ax = (unsigned short*)smem;            // [64][136] bf16  (17408 B)
    unsigned short* Wb = Ax + 64 * 136;                    // [128][136] bf16 (34816 B)
    unsigned short* Pb = Wb + 128 * 136;                   // [64][136] bf16  (17408 B)
    int*   toks = (int*)(smem + 69632);
    float* gats = (float*)(smem + 69632 + 256);
    float* Wh2l = (float*)(smem + 69632 + 512);            // 512 f
    float* bh2l = (float*)(smem + 69632 + 2560);           // 8 f
    float* bh1l = (float*)(smem + 69632 + 2592);           // 64 f

    int bid = blockIdx.x;
    int total = chunkpre[16];
    if (bid >= total) return;
    int t = 0;
    while (t < 15 && bid >= chunkpre[t + 1]) t++;
    int ci = bid - chunkpre[t];
    int nt = cnt[t];
    int base = offsets[t] + ci * 64;
    int nvalid = nt - ci * 64; if (nvalid > 64) nvalid = 64;

    int tid = threadIdx.x;
    if (tid < 64) {
        int tk = (tid < nvalid) ? bucket[base + tid] : -1;
        toks[tid] = tk;
        gats[tid] = (tk >= 0) ? gate[tk] : 0.0f;
    }
    // head params: 256 threads -> Wh2 (512), bh2 (8), bh1 (64)
    Wh2l[tid] = Wh2[tid];
    Wh2l[tid + 256] = Wh2[tid + 256];
    if (tid < 8) bh2l[tid] = bh2[tid];
    else if (tid < 72) bh1l[tid - 8] = bh1[tid - 8];
    __syncthreads();

    // stage x rows (gathered, zero-padded)
    #pragma unroll
    for (int it = 0; it < 4; it++) {
        int seg = it * 256 + tid; int r = seg >> 4, sg = seg & 15;
        int tk = toks[r];
        uintx4 v = {0u, 0u, 0u, 0u};
        if (tk >= 0) v = *(const uintx4*)(xq + (long)tk * 128 + sg * 8);
        *(uintx4*)(Ax + r * 136 + sg * 8) = v;
    }

    int lane = tid & 63, w = tid >> 6;
    int mh = w & 1, nh = w >> 1;
    int lane15 = lane & 15, lgrp = lane >> 4;

    floatx4 acc2[2][4];
    #pragma unroll
    for (int i = 0; i < 2; i++)
        #pragma unroll
        for (int j = 0; j < 4; j++) acc2[i][j] = (floatx4){0.f, 0.f, 0.f, 0.f};

    const unsigned short* W1base = W1qT + (long)t * 65536;
    const unsigned short* W2base = W2qT + (long)t * 65536;

    for (int nc = 0; nc < 4; nc++) {
        __syncthreads();   // prev GEMM2 done -> Wb free
        const unsigned short* g1 = W1base + nc * 16384;
        #pragma unroll
        for (int it = 0; it < 8; it++) {
            int seg = it * 256 + tid; int r = seg >> 4, sg = seg & 15;
            *(uintx4*)(Wb + r * 136 + sg * 8) = *(const uintx4*)(g1 + r * 128 + sg * 8);
        }
        __syncthreads();

        floatx4 acc1[2][4];
        #pragma unroll
        for (int i = 0; i < 2; i++)
            #pragma unroll
            for (int j = 0; j < 4; j++) acc1[i][j] = (floatx4){0.f, 0.f, 0.f, 0.f};

        #pragma unroll
        for (int kk = 0; kk < 4; kk++) {
            int ko = kk * 32 + lgrp * 8;
            short8 af0 = *(const short8*)(Ax + (mh * 32 + lane15) * 136 + ko);
            short8 af1 = *(const short8*)(Ax + (mh * 32 + 16 + lane15) * 136 + ko);
            #pragma unroll
            for (int ntt = 0; ntt < 4; ntt++) {
                short8 bf = *(const short8*)(Wb + (nh * 64 + ntt * 16 + lane15) * 136 + ko);
                acc1[0][ntt] = mfma16(af0, bf, acc1[0][ntt]);
                acc1[1][ntt] = mfma16(af1, bf, acc1[1][ntt]);
            }
        }

        // gelu -> P (bf16)
        #pragma unroll
        for (int mt2 = 0; mt2 < 2; mt2++) {
            int mb = mh * 32 + mt2 * 16 + lgrp * 4;
            #pragma unroll
            for (int ntt = 0; ntt < 4; ntt++) {
                int n = nh * 64 + ntt * 16 + lane15;
                floatx4 v = acc1[mt2][ntt];
                #pragma unroll
                for (int r = 0; r < 4; r++) {
                    float u = v[r];
                    float inner = 0.7978845608f * (u + 0.044715f * u * u * u);
                    inner = fminf(fmaxf(inner, -15.f), 15.f);
                    float e = __expf(2.0f * inner);
                    float th = (e - 1.0f) / (e + 1.0f);
                    Pb[(mb + r) * 136 + n] = f2bf(0.5f * u * (1.0f + th));
                }
            }
        }
        __syncthreads();   // GEMM1 Wb reads done + Pb written
        const unsigned short* g2 = W2base + nc * 128;
        #pragma unroll
        for (int it = 0; it < 8; it++) {
            int seg = it * 256 + tid; int r = seg >> 4, sg = seg & 15;
            *(uintx4*)(Wb + r * 136 + sg * 8) = *(const uintx4*)(g2 + (long)r * 512 + sg * 8);
        }
        __syncthreads();

        #pragma unroll
        for (int kk = 0; kk < 4; kk++) {
            int ko = kk * 32 + lgrp * 8;
            short8 af0 = *(const short8*)(Pb + (mh * 32 + lane15) * 136 + ko);
            short8 af1 = *(const short8*)(Pb + (mh * 32 + 16 + lane15) * 136 + ko);
            #pragma unroll
            for (int dt = 0; dt < 4; dt++) {
                short8 bf = *(const short8*)(Wb + (nh * 64 + dt * 16 + lane15) * 136 + ko);
                acc2[0][dt] = mfma16(af0, bf, acc2[0][dt]);
                acc2[1][dt] = mfma16(af1, bf, acc2[1][dt]);
            }
        }
    }

    __syncthreads();  // all GEMM2 done; Pb/Wb free
    // O = out*gate -> Pb (bf16); stage Wh1T -> Wb
    #pragma unroll
    for (int mt2 = 0; mt2 < 2; mt2++) {
        int mb = mh * 32 + mt2 * 16 + lgrp * 4;
        #pragma unroll
        for (int dt = 0; dt < 4; dt++) {
            int d = nh * 64 + dt * 16 + lane15;
            floatx4 v = acc2[mt2][dt];
            #pragma unroll
            for (int r = 0; r < 4; r++)
                Pb[(mb + r) * 136 + d] = f2bf(v[r] * gats[mb + r]);
        }
    }
    #pragma unroll
    for (int it = 0; it < 4; it++) {
        int seg = it * 256 + tid; int r = seg >> 4, sg = seg & 15;
        *(uintx4*)(Wb + r * 136 + sg * 8) = *(const uintx4*)(Wh1T + r * 128 + sg * 8);
    }
    __syncthreads();

    // GEMM3: [64 m] x [64 h], wave tile 32x32
    floatx4 acc3[2][2];
    #pragma unroll
    for (int i = 0; i < 2; i++)
        #pragma unroll
        for (int j = 0; j < 2; j++) acc3[i][j] = (floatx4){0.f, 0.f, 0.f, 0.f};
    #pragma unroll
    for (int kk = 0; kk < 4; kk++) {
        int ko = kk * 32 + lgrp * 8;
        short8 af0 = *(const short8*)(Pb + (mh * 32 + lane15) * 136 + ko);
        short8 af1 = *(const short8*)(Pb + (mh * 32 + 16 + lane15) * 136 + ko);
        #pragma unroll
        for (int ht = 0; ht < 2; ht++) {
            short8 bf = *(const short8*)(Wb + (nh * 32 + ht * 16 + lane15) * 136 + ko);
            acc3[0][ht] = mfma16(af0, bf, acc3[0][ht]);
            acc3[1][ht] = mfma16(af1, bf, acc3[1][ht]);
        }
    }
    __syncthreads();  // GEMM3 done; Ax reusable as H
    float* H = (float*)Ax;  // [64][66] f32
    #pragma unroll
    for (int mt2 = 0; mt2 < 2; mt2++) {
        int mb = mh * 32 + mt2 * 16 + lgrp * 4;
        #pragma unroll
        for (int ht = 0; ht < 2; ht++) {
            int h = nh * 32 + ht * 16 + lane15;
            floatx4 v = acc3[mt2][ht];
            #pragma unroll
            for (int r = 0; r < 4; r++)
                H[(mb + r) * 66 + h] = fmaxf(v[r] + bh1l[h], 0.0f);
        }
    }
    __syncthreads();

    // final: result = sigmoid(H @ Wh2 + bh2), 2 outputs per thread
    int mloc = tid >> 2, c0 = (tid & 3) * 2;
    int tk = toks[mloc];
    float z0 = bh2l[c0], z1 = bh2l[c0 + 1];
    const float* Hr = H + mloc * 66;
    #pragma unroll 8
    for (int h = 0; h < 64; h++) {
        float hv = Hr[h];
        z0 += hv * Wh2l[h * 8 + c0];
        z1 += hv * Wh2l[h * 8 + c0 + 1];
    }
    if (tk >= 0) {
        float2 rr;
        rr.x = 1.0f / (1.0f + __expf(-z0));
        rr.y = 1.0f / (1.0f + __expf(-z1));
        *(float2*)(result + (long)tk * 8 + c0) = rr;
    }
}

// ---------------- launch ----------------

extern "C" void kernel_launch(void* const* d_in, const int* in_sizes, int n_in,
                              void* d_out, int out_size, void* d_ws, size_t ws_size,
                              hipStream_t stream) {
    const int* op_idx = (const int*)d_in[0];
    const int* a_in   = (const int*)d_in[1];
    const int* b_in_i = (const int*)d_in[2];
    const int* c_in   = (const int*)d_in[3];
    const float* op_embed = (const float*)d_in[4];
    const float* W_in  = (const float*)d_in[5];
    const float* b_in  = (const float*)d_in[6];
    const float* Wr    = (const float*)d_in[7];
    const float* W1    = (const float*)d_in[8];
    const float* W2    = (const float*)d_in[9];
    const float* Wh1   = (const float*)d_in[10];
    const float* bh1   = (const float*)d_in[11];
    const float* Wh2   = (const float*)d_in[12];
    const float* bh2   = (const float*)d_in[13];

    const long B = in_sizes[0];  // 262144
    float* result = (float*)d_out;
    float* d_idx  = (float*)d_out + B * 8;
    float* d_aux  = (float*)d_out + B * 9;

    unsigned char* ws = (unsigned char*)d_ws;
    unsigned short* xq   = (unsigned short*)(ws + 0);               // 2*B*128
    unsigned short* W1qT = (unsigned short*)(ws + 67108864);
    unsigned short* W2qT = (unsigned short*)(ws + 69206016);
    unsigned short* Wh1T = (unsigned short*)(ws + 71303168);
    float* gate  = (float*)(ws + 71319552);
    int*   bucket= (int*)  (ws + 72368128);
    float* Ta    = (float*)(ws + 73416704);
    float* Tb    = (float*)(ws + 73547776);
    float* embW  = (float*)(ws + 73678848);
    float* Tc    = (float*)(ws + 73682944);
    float* TaR   = (float*)(ws + 73683456);
    float* TbR   = (float*)(ws + 73699840);
    float* embWr = (float*)(ws + 73716224);
    float* TcR   = (float*)(ws + 73716736);
    unsigned char* acc = ws + 73716800;
    float* s1sum   = (float*)(acc + 0);
    float* s2sum   = (float*)(acc + 64);
    float* ternsum = (float*)(acc + 128);
    float* psum    = (float*)(acc + 192);
    int*   cnt     = (int*)(acc + 256);
    int*   fill    = (int*)(acc + 320);
    int*   offsets = (int*)(acc + 384);
    int*   chunkpre= (int*)(acc + 452);

    hipMemsetAsync(acc, 0, 576, stream);

    k_sumabs<<<32, 256, 0, stream>>>(W1, W2, s1sum, s2sum);
    k_quant<<<8192, 256, 0, stream>>>(W1, W2, s1sum, s2sum, W1qT, W2qT, ternsum);
    k_tables<<<293, 256, 0, stream>>>(op_embed, W_in, b_in, Wh1, embW, Ta, Tb, Tc, Wh1T);
    k_tablesR<<<33, 256, 0, stream>>>(embW, Ta, Tb, Tc, Wr, embWr, TaR, TbR, TcR);
    k_front<<<(int)(B / 256), 256, 0, stream>>>(op_idx, a_in, b_in_i, c_in,
                                                embW, Ta, Tb, Tc, embWr, TaR, TbR, TcR,
                                                xq, gate, psum, cnt, d_idx);
    k_prefix_aux<<<1, 64, 0, stream>>>(cnt, psum, ternsum, offsets, chunkpre, d_aux, (float)B);
    k_scatter<<<(int)(B / 256), 256, 0, stream>>>(d_idx, offsets, fill, bucket);
    k_ffn<<<4112, 256, 72480, stream>>>(xq, gate, bucket, cnt, offsets, chunkpre,
                                        W1qT, W2qT, Wh1T, Wh2, bh1, bh2, result);
}

// Round 3
// 749.400 us; speedup vs baseline: 1.0644x; 1.0644x over previous
//
#include <hip/hip_runtime.h>
#include <hip/hip_bf16.h>
#include <math.h>

typedef __attribute__((ext_vector_type(8))) short short8;
typedef __attribute__((ext_vector_type(4))) float floatx4;
typedef __attribute__((ext_vector_type(4))) unsigned int uintx4;
typedef __attribute__((ext_vector_type(2))) unsigned int uintx2;

__device__ __forceinline__ unsigned short f2bf(float f) {
    unsigned int u = __float_as_uint(f);
    unsigned int r = (u + 0x7fffu + ((u >> 16) & 1u)) >> 16;
    return (unsigned short)r;
}

// pack two f32 -> bf16x2 (RNE), matches f2bf
__device__ __forceinline__ unsigned int pk2bf(float a, float b) {
    unsigned int ua = __float_as_uint(a);
    ua = ua + 0x7fffu + ((ua >> 16) & 1u);
    unsigned int ub = __float_as_uint(b);
    ub = ub + 0x7fffu + ((ub >> 16) & 1u);
    return (ua >> 16) | (ub & 0xffff0000u);
}

__device__ __forceinline__ float gelu_f(float u) {
    // tanh-gelu via sigmoid identity: 0.5u(1+tanh(z)) = u*sigmoid(2z)
    float u2 = u * u;
    float e = __expf(-1.5957691216f * u * (1.0f + 0.044715f * u2));
    return u * __builtin_amdgcn_rcpf(1.0f + e);
}

__device__ __forceinline__ floatx4 mfma16(short8 a, short8 b, floatx4 c) {
    return __builtin_amdgcn_mfma_f32_16x16x32_bf16(a, b, c, 0, 0, 0);
}

// ---------------- Phase A: weight reductions / quantization / tables ----------------

__global__ void k_sumabs(const float* __restrict__ W1, const float* __restrict__ W2,
                         float* s1sum, float* s2sum) {
    int b = blockIdx.x;
    const float* W = (b < 16) ? (W1 + (long)b * 65536) : (W2 + (long)(b - 16) * 65536);
    float s = 0.f;
    for (int i = threadIdx.x; i < 65536; i += 256) s += fabsf(W[i]);
    __shared__ float red[256];
    red[threadIdx.x] = s; __syncthreads();
    for (int st = 128; st > 0; st >>= 1) {
        if (threadIdx.x < st) red[threadIdx.x] += red[threadIdx.x + st];
        __syncthreads();
    }
    if (threadIdx.x == 0) { if (b < 16) s1sum[b] = red[0]; else s2sum[b - 16] = red[0]; }
}

__global__ void k_quant(const float* __restrict__ W1, const float* __restrict__ W2,
                        const float* __restrict__ s1sum, const float* __restrict__ s2sum,
                        unsigned short* __restrict__ W1qT, unsigned short* __restrict__ W2qT,
                        float* ternsum) {
    long e = (long)blockIdx.x * 256 + threadIdx.x;
    bool isW1 = e < 1048576;
    long el = isW1 ? e : e - 1048576;
    int t = (int)(el >> 16); int loc = (int)(el & 65535);
    float s = (isW1 ? s1sum[t] : s2sum[t]) * (1.0f / 65536.0f);
    float w = (isW1 ? W1 : W2)[el];
    float q = (fabsf(w) > 0.7f * s) ? (w > 0.f ? s : -s) : 0.0f;
    float d = fabsf(w - q);
    if (isW1) { int k = loc >> 9, n = loc & 511; W1qT[(long)t * 65536 + n * 128 + k] = f2bf(q); }
    else      { int kf = loc >> 7, dd = loc & 127; W2qT[(long)t * 65536 + dd * 512 + kf] = f2bf(q); }
    __shared__ float red[256];
    red[threadIdx.x] = d; __syncthreads();
    for (int st = 128; st > 0; st >>= 1) {
        if (threadIdx.x < st) red[threadIdx.x] += red[threadIdx.x + st];
        __syncthreads();
    }
    if (threadIdx.x == 0) atomicAdd(ternsum, red[0]);
}

__global__ void k_tables(const float* __restrict__ op_embed, const float* __restrict__ W_in,
                         const float* __restrict__ b_in, const float* __restrict__ Wh1,
                         float* embW, float* Ta, float* Tb, float* Tc,
                         unsigned short* Wh1T) {
    int i = blockIdx.x * 256 + threadIdx.x;
    if (i < 1024) {                      // embW' = op_embed@W_in[0:32] + b_in
        int op = i >> 7, j = i & 127;
        float s = b_in[j];
        #pragma unroll
        for (int k = 0; k < 32; k++) s += op_embed[op * 32 + k] * W_in[k * 128 + j];
        embW[i] = s;
    } else if (i < 1024 + 32768) {       // Ta[a] = bits(a)@W_in[32:40]
        int r = i - 1024; int a = r >> 7, j = r & 127;
        float s = 0.f;
        #pragma unroll
        for (int bit = 0; bit < 8; bit++) if ((a >> bit) & 1) s += W_in[(32 + bit) * 128 + j];
        Ta[r] = s;
    } else if (i < 1024 + 65536) {       // Tb[b] = bits(b)@W_in[40:48]
        int r = i - 33792; int b = r >> 7, j = r & 127;
        float s = 0.f;
        #pragma unroll
        for (int bit = 0; bit < 8; bit++) if ((b >> bit) & 1) s += W_in[(40 + bit) * 128 + j];
        Tb[r] = s;
    } else if (i < 66560 + 128) {        // Tc = W_in row 48
        int j = i - 66560; Tc[j] = W_in[48 * 128 + j];
    } else if (i < 66688 + 8192) {       // Wh1T[h][k] = Wh1[k][h] (bf16)
        int r = i - 66688; int h = r >> 7, k = r & 127;
        Wh1T[r] = f2bf(Wh1[k * 64 + h]);
    }
}

__global__ void k_tablesR(const float* __restrict__ embW, const float* __restrict__ Ta,
                          const float* __restrict__ Tb, const float* __restrict__ Tc,
                          const float* __restrict__ Wr,
                          float* embWr, float* TaR, float* TbR, float* TcR) {
    int i = blockIdx.x * 256 + threadIdx.x;
    int row = i >> 4, t = i & 15;
    const float* src; float* dst;
    if (row < 8)        { src = embW + row * 128;        dst = embWr + i; }
    else if (row < 264) { src = Ta + (row - 8) * 128;    dst = TaR + (row - 8) * 16 + t; }
    else if (row < 520) { src = Tb + (row - 264) * 128;  dst = TbR + (row - 264) * 16 + t; }
    else if (row == 520){ src = Tc;                      dst = TcR + t; }
    else return;
    float s = 0.f;
    for (int j = 0; j < 128; j++) s += src[j] * Wr[j * 16 + t];
    *dst = s;
}

// ---------------- Phase B: router + x, 16 lanes per token ----------------
// grid 1024x256, 16 iterations; shuffle-based softmax/argmax; register-accumulated
// psum/cnt with one global atomic per wave at the end.

__global__ __launch_bounds__(256) void k_front(
        const int* __restrict__ op_idx, const int* __restrict__ a_in,
        const int* __restrict__ b_in_i, const int* __restrict__ c_in,
        const float* __restrict__ embW, const float* __restrict__ Ta,
        const float* __restrict__ Tb, const float* __restrict__ Tc,
        const float* __restrict__ embWr, const float* __restrict__ TaR,
        const float* __restrict__ TbR, const float* __restrict__ TcR,
        unsigned short* __restrict__ xq, float* __restrict__ gate_out,
        float* psum, int* cnt, float* __restrict__ d_idx) {
    int gid = blockIdx.x * 256 + threadIdx.x;
    int lane = threadIdx.x & 63;
    int j = lane & 15;                   // logit index / dim-slice
    int grpbase = lane & 48;
    float psum_acc = 0.f; int cnt_acc = 0;

    #pragma unroll 1
    for (int it = 0; it < 16; it++) {
        int tok = it * 16384 + (gid >> 4);
        int op = op_idx[tok], a = a_in[tok], b = b_in_i[tok], c = c_in[tok];
        float cf = (float)c;

        // my logit
        float lg = embWr[op * 16 + j] + TaR[a * 16 + j] + TbR[b * 16 + j] + cf * TcR[j];
        // group max
        float m = lg;
        m = fmaxf(m, __shfl_xor(m, 8, 16));
        m = fmaxf(m, __shfl_xor(m, 4, 16));
        m = fmaxf(m, __shfl_xor(m, 2, 16));
        m = fmaxf(m, __shfl_xor(m, 1, 16));
        float p = __expf(lg - m);
        float s = p;
        s += __shfl_xor(s, 8, 16);
        s += __shfl_xor(s, 4, 16);
        s += __shfl_xor(s, 2, 16);
        s += __shfl_xor(s, 1, 16);
        float g = __builtin_amdgcn_rcpf(s);          // gate = max prob
        // argmax (first index of max)
        unsigned long long ball = __ballot(lg == m);
        int bi = __ffsll((unsigned long long)((ball >> grpbase) & 0xffffULL)) - 1;
        psum_acc += p * g;
        cnt_acc += (j == bi) ? 1 : 0;
        if (j == 0) { gate_out[tok] = g; d_idx[tok] = (float)bi; }

        // x dims j*8..j*8+7 (bf16), coalesced 16B store
        int d0 = j * 8;
        const floatx4* E  = (const floatx4*)(embW + op * 128 + d0);
        const floatx4* A4 = (const floatx4*)(Ta + a * 128 + d0);
        const floatx4* B4 = (const floatx4*)(Tb + b * 128 + d0);
        const floatx4* C4 = (const floatx4*)(Tc + d0);
        floatx4 v0 = E[0] + A4[0] + B4[0] + cf * C4[0];
        floatx4 v1 = E[1] + A4[1] + B4[1] + cf * C4[1];
        uintx4 o;
        o[0] = pk2bf(v0[0], v0[1]);
        o[1] = pk2bf(v0[2], v0[3]);
        o[2] = pk2bf(v1[0], v1[1]);
        o[3] = pk2bf(v1[2], v1[3]);
        *(uintx4*)(xq + (long)tok * 128 + d0) = o;
    }

    // fold 4 groups per wave, then one atomic per wave
    psum_acc += __shfl_xor(psum_acc, 16);
    psum_acc += __shfl_xor(psum_acc, 32);
    cnt_acc += __shfl_xor(cnt_acc, 16);
    cnt_acc += __shfl_xor(cnt_acc, 32);
    if (lane < 16) {
        atomicAdd(&psum[j], psum_acc);
        atomicAdd(&cnt[j], cnt_acc);
    }
}

// ---------------- prefix + aux (single thread) ----------------

__global__ void k_prefix_aux(const int* __restrict__ cnt, const float* __restrict__ psum,
                             const float* __restrict__ ternsum,
                             int* offsets, int* chunkpre, float* d_aux, float Bf) {
    if (threadIdx.x == 0 && blockIdx.x == 0) {
        int off = 0, coff = 0;
        for (int t = 0; t < 16; t++) {
            offsets[t] = off; chunkpre[t] = coff;
            off += cnt[t]; coff += (cnt[t] + 63) >> 6;
        }
        offsets[16] = off; chunkpre[16] = coff;
        float tern = ternsum[0] * (1.0f / 1048576.0f);
        float sp = 0.f; float cp[4] = {0.f, 0.f, 0.f, 0.f};
        for (int t = 0; t < 16; t++) {
            float frac = (float)cnt[t] / Bf, mp = psum[t] / Bf;
            sp += frac * mp; cp[t >> 2] += mp;
        }
        float dv = 0.f;
        for (int cc = 0; cc < 4; cc++) dv += cp[cc] * logf(cp[cc] + 1e-9f);
        d_aux[0] = 0.01f * tern + 0.005f * (16.0f * sp) + 0.01f * dv;
    }
}

// ---------------- scatter into per-tile buckets ----------------

__global__ void k_scatter(const float* __restrict__ d_idx, const int* __restrict__ offsets,
                          int* fill, int* __restrict__ bucket) {
    __shared__ int lc[16], lbase[16];
    if (threadIdx.x < 16) lc[threadIdx.x] = 0;
    __syncthreads();
    int tok = blockIdx.x * 256 + threadIdx.x;
    int t = (int)d_idx[tok];
    int lpos = atomicAdd(&lc[t], 1);
    __syncthreads();
    if (threadIdx.x < 16) lbase[threadIdx.x] = atomicAdd(&fill[threadIdx.x], lc[threadIdx.x]);
    __syncthreads();
    bucket[offsets[t] + lbase[t] + lpos] = tok;
}

// ---------------- Phase C: MoE FFN + head (MFMA, transposed epilogues) ----------------
// GEMM1 computes P^T (A=W1 rows, B=X rows)  -> lane holds 4 consecutive k2 of one m row
//   -> gelu+pack -> ds_write_b64 into Pb[m][k2]
// GEMM2 computes Out^T (A=W2 rows, B=P rows) -> b64 writes into Ob[m][d] (alias Ax)
// GEMM3 computes H^T (A=Wh1T rows, B=Ob rows) -> b128 writes into H[m][h] f32 (alias Pb)

__global__ __launch_bounds__(256) void k_ffn(
    const unsigned short* __restrict__ xq, const float* __restrict__ gate,
    const int* __restrict__ bucket, const int* __restrict__ cnt,
    const int* __restrict__ offsets, const int* __restrict__ chunkpre,
    const unsigned short* __restrict__ W1qT, const unsigned short* __restrict__ W2qT,
    const unsigned short* __restrict__ Wh1T, const float* __restrict__ Wh2,
    const float* __restrict__ bh1, const float* __restrict__ bh2,
    float* __restrict__ result) {

    extern __shared__ __align__(16) unsigned char smem[];
    unsigned short* Ax = (unsigned short*)smem;            // [64][136] bf16 (17408 B); later Ob
    unsigned short* Wb = Ax + 64 * 136;                    // [128][136] bf16 (34816 B)
    unsigned short* Pb = Wb + 128 * 136;                   // [64][136] bf16 (17408 B); later H f32 [64][68]
    int*   toks = (int*)(smem + 69632);
    float* gats = (float*)(smem + 69632 + 256);
    float* Wh2l = (float*)(smem + 69632 + 512);            // 512 f
    float* bh2l = (float*)(smem + 72192);                  // 8 f
    float* bh1l = (float*)(smem + 72224);                  // 64 f

    int bid = blockIdx.x;
    int total = chunkpre[16];
    if (bid >= total) return;
    int t = 0;
    while (t < 15 && bid >= chunkpre[t + 1]) t++;
    int ci = bid - chunkpre[t];
    int nt = cnt[t];
    int base = offsets[t] + ci * 64;
    int nvalid = nt - ci * 64; if (nvalid > 64) nvalid = 64;

    int tid = threadIdx.x;
    if (tid < 64) {
        int tk = (tid < nvalid) ? bucket[base + tid] : -1;
        toks[tid] = tk;
        gats[tid] = (tk >= 0) ? gate[tk] : 0.0f;
    }
    Wh2l[tid] = Wh2[tid];
    Wh2l[tid + 256] = Wh2[tid + 256];
    if (tid < 8) bh2l[tid] = bh2[tid];
    else if (tid < 72) bh1l[tid - 8] = bh1[tid - 8];
    __syncthreads();

    // stage x rows (gathered, zero-padded)
    #pragma unroll
    for (int it = 0; it < 4; it++) {
        int seg = it * 256 + tid; int r = seg >> 4, sg = seg & 15;
        int tk = toks[r];
        uintx4 v = {0u, 0u, 0u, 0u};
        if (tk >= 0) v = *(const uintx4*)(xq + (long)tk * 128 + sg * 8);
        *(uintx4*)(Ax + r * 136 + sg * 8) = v;
    }

    int lane = tid & 63, dh = tid >> 6;          // wave id = row-block
    int lane15 = lane & 15, lgrp = lane >> 4;

    floatx4 acc2[2][4];
    #pragma unroll
    for (int i = 0; i < 2; i++)
        #pragma unroll
        for (int j = 0; j < 4; j++) acc2[i][j] = (floatx4){0.f, 0.f, 0.f, 0.f};

    const unsigned short* W1base = W1qT + (long)t * 65536;
    const unsigned short* W2base = W2qT + (long)t * 65536;

    for (int nc = 0; nc < 4; nc++) {
        __syncthreads();                         // Wb free (prev GEMM2 done), Pb readers done
        const unsigned short* g1 = W1base + nc * 16384;
        #pragma unroll
        for (int it = 0; it < 8; it++) {
            int seg = it * 256 + tid; int r = seg >> 4, sg = seg & 15;
            *(uintx4*)(Wb + r * 136 + sg * 8) = *(const uintx4*)(g1 + r * 128 + sg * 8);
        }
        __syncthreads();

        // GEMM1: P^T chunk [128 n][64 m]; wave dh: n-tiles 2dh,2dh+1; m-tiles 0..3
        floatx4 acc1[2][4];
        #pragma unroll
        for (int i = 0; i < 2; i++)
            #pragma unroll
            for (int j = 0; j < 4; j++) acc1[i][j] = (floatx4){0.f, 0.f, 0.f, 0.f};

        #pragma unroll
        for (int kk = 0; kk < 4; kk++) {
            int ko = kk * 32 + lgrp * 8;
            short8 af0 = *(const short8*)(Wb + (dh * 32 + lane15) * 136 + ko);
            short8 af1 = *(const short8*)(Wb + (dh * 32 + 16 + lane15) * 136 + ko);
            #pragma unroll
            for (int mt = 0; mt < 4; mt++) {
                short8 bf = *(const short8*)(Ax + (mt * 16 + lane15) * 136 + ko);
                acc1[0][mt] = mfma16(af0, bf, acc1[0][mt]);
                acc1[1][mt] = mfma16(af1, bf, acc1[1][mt]);
            }
        }
        __syncthreads();                         // GEMM1 Wb reads done; Pb free

        // epilogue: gelu -> Pb[m][k2local] (b64 writes) ; stage W2 chunk -> Wb
        #pragma unroll
        for (int i = 0; i < 2; i++) {
            int k2b = dh * 32 + i * 16 + lgrp * 4;
            #pragma unroll
            for (int mt = 0; mt < 4; mt++) {
                int m = mt * 16 + lane15;
                floatx4 v = acc1[i][mt];
                float g0 = gelu_f(v[0]), g1v = gelu_f(v[1]);
                float g2v = gelu_f(v[2]), g3 = gelu_f(v[3]);
                uintx2 o; o[0] = pk2bf(g0, g1v); o[1] = pk2bf(g2v, g3);
                *(uintx2*)(Pb + m * 136 + k2b) = o;
            }
        }
        const unsigned short* g2 = W2base + nc * 128;
        #pragma unroll
        for (int it = 0; it < 8; it++) {
            int seg = it * 256 + tid; int r = seg >> 4, sg = seg & 15;
            *(uintx4*)(Wb + r * 136 + sg * 8) = *(const uintx4*)(g2 + (long)r * 512 + sg * 8);
        }
        __syncthreads();

        // GEMM2: Out^T [128 d][64 m] accumulate across nc
        #pragma unroll
        for (int kk = 0; kk < 4; kk++) {
            int ko = kk * 32 + lgrp * 8;
            short8 af0 = *(const short8*)(Wb + (dh * 32 + lane15) * 136 + ko);
            short8 af1 = *(const short8*)(Wb + (dh * 32 + 16 + lane15) * 136 + ko);
            #pragma unroll
            for (int mt = 0; mt < 4; mt++) {
                short8 bf = *(const short8*)(Pb + (mt * 16 + lane15) * 136 + ko);
                acc2[0][mt] = mfma16(af0, bf, acc2[0][mt]);
                acc2[1][mt] = mfma16(af1, bf, acc2[1][mt]);
            }
        }
    }

    __syncthreads();                             // all GEMM2 reads done; Ax,Wb,Pb free
    unsigned short* Ob = Ax;                     // [64 m][136] bf16: Out*gate
    #pragma unroll
    for (int i = 0; i < 2; i++) {
        int db = dh * 32 + i * 16 + lgrp * 4;
        #pragma unroll
        for (int mt = 0; mt < 4; mt++) {
            int m = mt * 16 + lane15;
            float gm = gats[m];
            floatx4 v = acc2[i][mt];
            uintx2 o; o[0] = pk2bf(v[0] * gm, v[1] * gm); o[1] = pk2bf(v[2] * gm, v[3] * gm);
            *(uintx2*)(Ob + m * 136 + db) = o;
        }
    }
    // stage Wh1T [64][128] -> Wb
    #pragma unroll
    for (int it = 0; it < 4; it++) {
        int seg = it * 256 + tid; int r = seg >> 4, sg = seg & 15;
        *(uintx4*)(Wb + r * 136 + sg * 8) = *(const uintx4*)(Wh1T + r * 128 + sg * 8);
    }
    __syncthreads();

    // GEMM3: H^T [64 h][64 m]; wave dh: h-tile dh; m-tiles 0..3
    floatx4 acc3[4];
    #pragma unroll
    for (int j = 0; j < 4; j++) acc3[j] = (floatx4){0.f, 0.f, 0.f, 0.f};
    #pragma unroll
    for (int kk = 0; kk < 4; kk++) {
        int ko = kk * 32 + lgrp * 8;
        short8 af = *(const short8*)(Wb + (dh * 16 + lane15) * 136 + ko);
        #pragma unroll
        for (int mt = 0; mt < 4; mt++) {
            short8 bf = *(const short8*)(Ob + (mt * 16 + lane15) * 136 + ko);
            acc3[mt] = mfma16(af, bf, acc3[mt]);
        }
    }
    __syncthreads();                             // GEMM3 Ob/Wb reads... Pb free for H
    float* H = (float*)Pb;                       // [64 m][68] f32
    int hb = dh * 16 + lgrp * 4;
    floatx4 b4 = *(const floatx4*)(bh1l + hb);
    #pragma unroll
    for (int mt = 0; mt < 4; mt++) {
        int m = mt * 16 + lane15;
        floatx4 v = acc3[mt] + b4;
        floatx4 hv;
        hv[0] = fmaxf(v[0], 0.f); hv[1] = fmaxf(v[1], 0.f);
        hv[2] = fmaxf(v[2], 0.f); hv[3] = fmaxf(v[3], 0.f);
        *(floatx4*)(H + m * 68 + hb) = hv;
    }
    __syncthreads();

    // final: result = sigmoid(H @ Wh2 + bh2), 2 outputs per thread
    int mloc = tid >> 2, c0 = (tid & 3) * 2;
    int tk = toks[mloc];
    float z0 = bh2l[c0], z1 = bh2l[c0 + 1];
    const floatx4* Hr4 = (const floatx4*)(H + mloc * 68);
    #pragma unroll
    for (int h4 = 0; h4 < 16; h4++) {
        floatx4 hv = Hr4[h4];
        #pragma unroll
        for (int r = 0; r < 4; r++) {
            int h = h4 * 4 + r;
            z0 += hv[r] * Wh2l[h * 8 + c0];
            z1 += hv[r] * Wh2l[h * 8 + c0 + 1];
        }
    }
    if (tk >= 0) {
        float2 rr;
        rr.x = __builtin_amdgcn_rcpf(1.0f + __expf(-z0));
        rr.y = __builtin_amdgcn_rcpf(1.0f + __expf(-z1));
        *(float2*)(result + (long)tk * 8 + c0) = rr;
    }
}

// ---------------- launch ----------------

extern "C" void kernel_launch(void* const* d_in, const int* in_sizes, int n_in,
                              void* d_out, int out_size, void* d_ws, size_t ws_size,
                              hipStream_t stream) {
    const int* op_idx = (const int*)d_in[0];
    const int* a_in   = (const int*)d_in[1];
    const int* b_in_i = (const int*)d_in[2];
    const int* c_in   = (const int*)d_in[3];
    const float* op_embed = (const float*)d_in[4];
    const float* W_in  = (const float*)d_in[5];
    const float* b_in  = (const float*)d_in[6];
    const float* Wr    = (const float*)d_in[7];
    const float* W1    = (const float*)d_in[8];
    const float* W2    = (const float*)d_in[9];
    const float* Wh1   = (const float*)d_in[10];
    const float* bh1   = (const float*)d_in[11];
    const float* Wh2   = (const float*)d_in[12];
    const float* bh2   = (const float*)d_in[13];

    const long B = in_sizes[0];  // 262144
    float* result = (float*)d_out;
    float* d_idx  = (float*)d_out + B * 8;
    float* d_aux  = (float*)d_out + B * 9;

    unsigned char* ws = (unsigned char*)d_ws;
    unsigned short* xq   = (unsigned short*)(ws + 0);               // 2*B*128
    unsigned short* W1qT = (unsigned short*)(ws + 67108864);
    unsigned short* W2qT = (unsigned short*)(ws + 69206016);
    unsigned short* Wh1T = (unsigned short*)(ws + 71303168);
    float* gate  = (float*)(ws + 71319552);
    int*   bucket= (int*)  (ws + 72368128);
    float* Ta    = (float*)(ws + 73416704);
    float* Tb    = (float*)(ws + 73547776);
    float* embW  = (float*)(ws + 73678848);
    float* Tc    = (float*)(ws + 73682944);
    float* TaR   = (float*)(ws + 73683456);
    float* TbR   = (float*)(ws + 73699840);
    float* embWr = (float*)(ws + 73716224);
    float* TcR   = (float*)(ws + 73716736);
    unsigned char* acc = ws + 73716800;
    float* s1sum   = (float*)(acc + 0);
    float* s2sum   = (float*)(acc + 64);
    float* ternsum = (float*)(acc + 128);
    float* psum    = (float*)(acc + 192);
    int*   cnt     = (int*)(acc + 256);
    int*   fill    = (int*)(acc + 320);
    int*   offsets = (int*)(acc + 384);
    int*   chunkpre= (int*)(acc + 452);

    hipMemsetAsync(acc, 0, 576, stream);

    k_sumabs<<<32, 256, 0, stream>>>(W1, W2, s1sum, s2sum);
    k_quant<<<8192, 256, 0, stream>>>(W1, W2, s1sum, s2sum, W1qT, W2qT, ternsum);
    k_tables<<<293, 256, 0, stream>>>(op_embed, W_in, b_in, Wh1, embW, Ta, Tb, Tc, Wh1T);
    k_tablesR<<<33, 256, 0, stream>>>(embW, Ta, Tb, Tc, Wr, embWr, TaR, TbR, TcR);
    k_front<<<1024, 256, 0, stream>>>(op_idx, a_in, b_in_i, c_in,
                                      embW, Ta, Tb, Tc, embWr, TaR, TbR, TcR,
                                      xq, gate, psum, cnt, d_idx);
    k_prefix_aux<<<1, 64, 0, stream>>>(cnt, psum, ternsum, offsets, chunkpre, d_aux, (float)B);
    k_scatter<<<(int)(B / 256), 256, 0, stream>>>(d_idx, offsets, fill, bucket);
    k_ffn<<<4112, 256, 72480, stream>>>(xq, gate, bucket, cnt, offsets, chunkpre,
                                        W1qT, W2qT, Wh1T, Wh2, bh1, bh2, result);
}

// Round 4
// 381.881 us; speedup vs baseline: 2.0888x; 1.9624x over previous
//
#include <hip/hip_runtime.h>
#include <hip/hip_bf16.h>
#include <math.h>

typedef __attribute__((ext_vector_type(8))) short short8;
typedef __attribute__((ext_vector_type(4))) float floatx4;
typedef __attribute__((ext_vector_type(4))) unsigned int uintx4;
typedef __attribute__((ext_vector_type(2))) unsigned int uintx2;

__device__ __forceinline__ unsigned short f2bf(float f) {
    unsigned int u = __float_as_uint(f);
    unsigned int r = (u + 0x7fffu + ((u >> 16) & 1u)) >> 16;
    return (unsigned short)r;
}

__device__ __forceinline__ unsigned int pk2bf(float a, float b) {
    unsigned int ua = __float_as_uint(a);
    ua = ua + 0x7fffu + ((ua >> 16) & 1u);
    unsigned int ub = __float_as_uint(b);
    ub = ub + 0x7fffu + ((ub >> 16) & 1u);
    return (ua >> 16) | (ub & 0xffff0000u);
}

__device__ __forceinline__ float gelu_f(float u) {
    float u2 = u * u;
    float e = __expf(-1.5957691216f * u * (1.0f + 0.044715f * u2));
    return u * __builtin_amdgcn_rcpf(1.0f + e);
}

__device__ __forceinline__ floatx4 mfma16(short8 a, short8 b, floatx4 c) {
    return __builtin_amdgcn_mfma_f32_16x16x32_bf16(a, b, c, 0, 0, 0);
}

// ---------------- Phase A ----------------

__global__ void k_sumabs(const float* __restrict__ W1, const float* __restrict__ W2,
                         float* s1sum, float* s2sum) {
    int b = blockIdx.x;
    const float* W = (b < 16) ? (W1 + (long)b * 65536) : (W2 + (long)(b - 16) * 65536);
    float s = 0.f;
    for (int i = threadIdx.x; i < 65536; i += 256) s += fabsf(W[i]);
    __shared__ float red[256];
    red[threadIdx.x] = s; __syncthreads();
    for (int st = 128; st > 0; st >>= 1) {
        if (threadIdx.x < st) red[threadIdx.x] += red[threadIdx.x + st];
        __syncthreads();
    }
    if (threadIdx.x == 0) { if (b < 16) s1sum[b] = red[0]; else s2sum[b - 16] = red[0]; }
}

// 512 blocks x 256 threads x 16 elems; one ternsum atomic per block
__global__ __launch_bounds__(256) void k_quant(
        const float* __restrict__ W1, const float* __restrict__ W2,
        const float* __restrict__ s1sum, const float* __restrict__ s2sum,
        unsigned short* __restrict__ W1qT, unsigned short* __restrict__ W2qT,
        float* ternsum) {
    int blk = blockIdx.x;
    bool isW1 = blk < 256;
    long el0 = (long)(isW1 ? blk : blk - 256) * 4096;
    int t = (int)(el0 >> 16);
    float s = (isW1 ? s1sum[t] : s2sum[t]) * (1.0f / 65536.0f);
    float thr = 0.7f * s;
    const float* Wsrc = (isW1 ? W1 : W2) + el0;
    unsigned short* dst = (isW1 ? W1qT : W2qT) + (long)t * 65536;
    int locbase = (int)(el0 & 65535);
    float dsum = 0.f;
    #pragma unroll
    for (int i = 0; i < 4; i++) {
        int off = i * 1024 + threadIdx.x * 4;
        floatx4 w = *(const floatx4*)(Wsrc + off);
        int loc = locbase + off;
        #pragma unroll
        for (int r = 0; r < 4; r++) {
            float wv = w[r];
            float q = (fabsf(wv) > thr) ? (wv > 0.f ? s : -s) : 0.f;
            dsum += fabsf(wv - q);
            int lr = loc + r;
            int addr = isW1 ? ((lr & 511) * 128 + (lr >> 9))
                            : ((lr & 127) * 512 + (lr >> 7));
            dst[addr] = f2bf(q);
        }
    }
    __shared__ float red[256];
    red[threadIdx.x] = dsum; __syncthreads();
    for (int st2 = 128; st2 > 0; st2 >>= 1) {
        if (threadIdx.x < st2) red[threadIdx.x] += red[threadIdx.x + st2];
        __syncthreads();
    }
    if (threadIdx.x == 0) atomicAdd(ternsum, red[0]);
}

__global__ void k_tables(const float* __restrict__ op_embed, const float* __restrict__ W_in,
                         const float* __restrict__ b_in, const float* __restrict__ Wh1,
                         float* embW, float* Ta, float* Tb, float* Tc,
                         unsigned short* Wh1T) {
    int i = blockIdx.x * 256 + threadIdx.x;
    if (i < 1024) {
        int op = i >> 7, j = i & 127;
        float s = b_in[j];
        #pragma unroll
        for (int k = 0; k < 32; k++) s += op_embed[op * 32 + k] * W_in[k * 128 + j];
        embW[i] = s;
    } else if (i < 1024 + 32768) {
        int r = i - 1024; int a = r >> 7, j = r & 127;
        float s = 0.f;
        #pragma unroll
        for (int bit = 0; bit < 8; bit++) if ((a >> bit) & 1) s += W_in[(32 + bit) * 128 + j];
        Ta[r] = s;
    } else if (i < 1024 + 65536) {
        int r = i - 33792; int b = r >> 7, j = r & 127;
        float s = 0.f;
        #pragma unroll
        for (int bit = 0; bit < 8; bit++) if ((b >> bit) & 1) s += W_in[(40 + bit) * 128 + j];
        Tb[r] = s;
    } else if (i < 66560 + 128) {
        int j = i - 66560; Tc[j] = W_in[48 * 128 + j];
    } else if (i < 66688 + 8192) {
        int r = i - 66688; int h = r >> 7, k = r & 127;
        Wh1T[r] = f2bf(Wh1[k * 64 + h]);
    }
}

__global__ void k_tablesR(const float* __restrict__ embW, const float* __restrict__ Ta,
                          const float* __restrict__ Tb, const float* __restrict__ Tc,
                          const float* __restrict__ Wr,
                          float* embWr, float* TaR, float* TbR, float* TcR) {
    int i = blockIdx.x * 256 + threadIdx.x;
    int row = i >> 4, t = i & 15;
    const float* src; float* dst;
    if (row < 8)        { src = embW + row * 128;        dst = embWr + i; }
    else if (row < 264) { src = Ta + (row - 8) * 128;    dst = TaR + (row - 8) * 16 + t; }
    else if (row < 520) { src = Tb + (row - 264) * 128;  dst = TbR + (row - 264) * 16 + t; }
    else if (row == 520){ src = Tc;                      dst = TcR + t; }
    else return;
    float s = 0.f;
    for (int j = 0; j < 128; j++) s += src[j] * Wr[j * 16 + t];
    *dst = s;
}

// ---------------- Phase B: router + x, 16 lanes per token ----------------

__global__ __launch_bounds__(256) void k_front(
        const int* __restrict__ op_idx, const int* __restrict__ a_in,
        const int* __restrict__ b_in_i, const int* __restrict__ c_in,
        const float* __restrict__ embW, const float* __restrict__ Ta,
        const float* __restrict__ Tb, const float* __restrict__ Tc,
        const float* __restrict__ embWr, const float* __restrict__ TaR,
        const float* __restrict__ TbR, const float* __restrict__ TcR,
        unsigned short* __restrict__ xq, float* __restrict__ gate_out,
        float* psum, int* cnt, float* __restrict__ d_idx) {
    __shared__ float sp[4][16];
    __shared__ int sc[4][16];
    int gid = blockIdx.x * 256 + threadIdx.x;
    int lane = threadIdx.x & 63;
    int j = lane & 15;
    int grpbase = lane & 48;
    float psum_acc = 0.f; int cnt_acc = 0;

    #pragma unroll 1
    for (int it = 0; it < 16; it++) {
        int tok = it * 16384 + (gid >> 4);
        int op = op_idx[tok], a = a_in[tok], b = b_in_i[tok], c = c_in[tok];
        float cf = (float)c;

        float lg = embWr[op * 16 + j] + TaR[a * 16 + j] + TbR[b * 16 + j] + cf * TcR[j];
        float m = lg;
        m = fmaxf(m, __shfl_xor(m, 8, 16));
        m = fmaxf(m, __shfl_xor(m, 4, 16));
        m = fmaxf(m, __shfl_xor(m, 2, 16));
        m = fmaxf(m, __shfl_xor(m, 1, 16));
        float p = __expf(lg - m);
        float s = p;
        s += __shfl_xor(s, 8, 16);
        s += __shfl_xor(s, 4, 16);
        s += __shfl_xor(s, 2, 16);
        s += __shfl_xor(s, 1, 16);
        float g = __builtin_amdgcn_rcpf(s);
        unsigned long long ball = __ballot(lg == m);
        int bi = __ffsll((unsigned long long)((ball >> grpbase) & 0xffffULL)) - 1;
        psum_acc += p * g;
        cnt_acc += (j == bi) ? 1 : 0;
        if (j == 0) { gate_out[tok] = g; d_idx[tok] = (float)bi; }

        int d0 = j * 8;
        const floatx4* E  = (const floatx4*)(embW + op * 128 + d0);
        const floatx4* A4 = (const floatx4*)(Ta + a * 128 + d0);
        const floatx4* B4 = (const floatx4*)(Tb + b * 128 + d0);
        const floatx4* C4 = (const floatx4*)(Tc + d0);
        floatx4 v0 = E[0] + A4[0] + B4[0] + cf * C4[0];
        floatx4 v1 = E[1] + A4[1] + B4[1] + cf * C4[1];
        uintx4 o;
        o[0] = pk2bf(v0[0], v0[1]);
        o[1] = pk2bf(v0[2], v0[3]);
        o[2] = pk2bf(v1[0], v1[1]);
        o[3] = pk2bf(v1[2], v1[3]);
        *(uintx4*)(xq + (long)tok * 128 + d0) = o;
    }

    psum_acc += __shfl_xor(psum_acc, 16);
    psum_acc += __shfl_xor(psum_acc, 32);
    cnt_acc += __shfl_xor(cnt_acc, 16);
    cnt_acc += __shfl_xor(cnt_acc, 32);
    int wv = threadIdx.x >> 6;
    if (lane < 16) { sp[wv][j] = psum_acc; sc[wv][j] = cnt_acc; }
    __syncthreads();
    if (threadIdx.x < 16) {
        int jj = threadIdx.x;
        atomicAdd(&psum[jj], sp[0][jj] + sp[1][jj] + sp[2][jj] + sp[3][jj]);
        atomicAdd(&cnt[jj], sc[0][jj] + sc[1][jj] + sc[2][jj] + sc[3][jj]);
    }
}

// ---------------- prefix + aux ----------------

__global__ void k_prefix_aux(const int* __restrict__ cnt, const float* __restrict__ psum,
                             const float* __restrict__ ternsum,
                             int* offsets, int* chunkpre, float* d_aux, float Bf) {
    if (threadIdx.x == 0 && blockIdx.x == 0) {
        int off = 0, coff = 0;
        for (int t = 0; t < 16; t++) {
            offsets[t] = off; chunkpre[t] = coff;
            off += cnt[t]; coff += (cnt[t] + 63) >> 6;
        }
        offsets[16] = off; chunkpre[16] = coff;
        float tern = ternsum[0] * (1.0f / 1048576.0f);
        float sp = 0.f; float cp[4] = {0.f, 0.f, 0.f, 0.f};
        for (int t = 0; t < 16; t++) {
            float frac = (float)cnt[t] / Bf, mp = psum[t] / Bf;
            sp += frac * mp; cp[t >> 2] += mp;
        }
        float dv = 0.f;
        for (int cc = 0; cc < 4; cc++) dv += cp[cc] * logf(cp[cc] + 1e-9f);
        d_aux[0] = 0.01f * tern + 0.005f * (16.0f * sp) + 0.01f * dv;
    }
}

// ---------------- scatter ----------------

__global__ void k_scatter(const float* __restrict__ d_idx, const int* __restrict__ offsets,
                          int* fill, int* __restrict__ bucket) {
    __shared__ int lc[16], lbase[16];
    if (threadIdx.x < 16) lc[threadIdx.x] = 0;
    __syncthreads();
    int tok = blockIdx.x * 256 + threadIdx.x;
    int t = (int)d_idx[tok];
    int lpos = atomicAdd(&lc[t], 1);
    __syncthreads();
    if (threadIdx.x < 16) lbase[threadIdx.x] = atomicAdd(&fill[threadIdx.x], lc[threadIdx.x]);
    __syncthreads();
    bucket[offsets[t] + lbase[t] + lpos] = tok;
}

// ---------------- Phase C: MoE FFN + head ----------------
// W1/W2/Wh1 A-fragments load directly global->VGPR (L2-resident, 16 lines/instr
// coalescing); LDS only stages X (Ax), P (Pb), Ob, H. 37.7 KB LDS -> 4 blocks/CU.

__global__ __launch_bounds__(256, 4) void k_ffn(
    const unsigned short* __restrict__ xq, const float* __restrict__ gate,
    const int* __restrict__ bucket, const int* __restrict__ cnt,
    const int* __restrict__ offsets, const int* __restrict__ chunkpre,
    const unsigned short* __restrict__ W1qT, const unsigned short* __restrict__ W2qT,
    const unsigned short* __restrict__ Wh1T, const float* __restrict__ Wh2,
    const float* __restrict__ bh1, const float* __restrict__ bh2,
    float* __restrict__ result) {

    extern __shared__ __align__(16) unsigned char smem[];
    unsigned short* Ax = (unsigned short*)smem;            // [64][136] bf16; later Ob
    unsigned short* Pb = Ax + 64 * 136;                    // [64][136] bf16; later H f32 [64][68]
    int*   toks = (int*)(smem + 34816);
    float* gats = (float*)(smem + 35072);
    float* Wh2l = (float*)(smem + 35328);                  // 512 f
    float* bh2l = (float*)(smem + 37376);                  // 8 f
    float* bh1l = (float*)(smem + 37408);                  // 64 f

    int bid = blockIdx.x;
    int total = chunkpre[16];
    if (bid >= total) return;
    int t = 0;
    while (t < 15 && bid >= chunkpre[t + 1]) t++;
    int ci = bid - chunkpre[t];
    int nt = cnt[t];
    int base = offsets[t] + ci * 64;
    int nvalid = nt - ci * 64; if (nvalid > 64) nvalid = 64;

    int tid = threadIdx.x;
    if (tid < 64) {
        int tk = (tid < nvalid) ? bucket[base + tid] : -1;
        toks[tid] = tk;
        gats[tid] = (tk >= 0) ? gate[tk] : 0.0f;
    }
    Wh2l[tid] = Wh2[tid];
    Wh2l[tid + 256] = Wh2[tid + 256];
    if (tid < 8) bh2l[tid] = bh2[tid];
    else if (tid < 72) bh1l[tid - 8] = bh1[tid - 8];
    __syncthreads();

    // stage x rows (gathered, zero-padded)
    #pragma unroll
    for (int it = 0; it < 4; it++) {
        int seg = it * 256 + tid; int r = seg >> 4, sg = seg & 15;
        int tk = toks[r];
        uintx4 v = {0u, 0u, 0u, 0u};
        if (tk >= 0) v = *(const uintx4*)(xq + (long)tk * 128 + sg * 8);
        *(uintx4*)(Ax + r * 136 + sg * 8) = v;
    }
    __syncthreads();

    int lane = tid & 63, dh = tid >> 6;
    int lane15 = lane & 15, lgrp = lane >> 4;

    floatx4 acc2[2][4];
    #pragma unroll
    for (int i = 0; i < 2; i++)
        #pragma unroll
        for (int j = 0; j < 4; j++) acc2[i][j] = (floatx4){0.f, 0.f, 0.f, 0.f};

    // per-lane W pointers (A fragments read straight from global/L2)
    const unsigned short* w1p = W1qT + (long)t * 65536 + (dh * 32 + lane15) * 128 + lgrp * 8;
    const unsigned short* w2p = W2qT + (long)t * 65536 + (dh * 32 + lane15) * 512 + lgrp * 8;
    const unsigned short* w3p = Wh1T + (dh * 16 + lane15) * 128 + lgrp * 8;

    for (int nc = 0; nc < 4; nc++) {
        // GEMM1: P^T chunk; A = W1 rows (global), B = Ax (LDS)
        floatx4 acc1[2][4];
        #pragma unroll
        for (int i = 0; i < 2; i++)
            #pragma unroll
            for (int j = 0; j < 4; j++) acc1[i][j] = (floatx4){0.f, 0.f, 0.f, 0.f};

        const unsigned short* w1c = w1p + nc * 16384;
        #pragma unroll
        for (int kk = 0; kk < 4; kk++) {
            short8 af0 = *(const short8*)(w1c + kk * 32);
            short8 af1 = *(const short8*)(w1c + 2048 + kk * 32);
            int ko = kk * 32 + lgrp * 8;
            #pragma unroll
            for (int mt = 0; mt < 4; mt++) {
                short8 bf = *(const short8*)(Ax + (mt * 16 + lane15) * 136 + ko);
                acc1[0][mt] = mfma16(af0, bf, acc1[0][mt]);
                acc1[1][mt] = mfma16(af1, bf, acc1[1][mt]);
            }
        }
        __syncthreads();                     // prev GEMM2's Pb reads done

        // gelu -> Pb[m][k2local] (b64 writes)
        #pragma unroll
        for (int i = 0; i < 2; i++) {
            int k2b = dh * 32 + i * 16 + lgrp * 4;
            #pragma unroll
            for (int mt = 0; mt < 4; mt++) {
                int m = mt * 16 + lane15;
                floatx4 v = acc1[i][mt];
                float g0 = gelu_f(v[0]), g1v = gelu_f(v[1]);
                float g2v = gelu_f(v[2]), g3 = gelu_f(v[3]);
                uintx2 o; o[0] = pk2bf(g0, g1v); o[1] = pk2bf(g2v, g3);
                *(uintx2*)(Pb + m * 136 + k2b) = o;
            }
        }
        __syncthreads();                     // Pb ready

        // GEMM2: Out^T; A = W2 rows (global), B = Pb (LDS)
        const unsigned short* w2c = w2p + nc * 128;
        #pragma unroll
        for (int kk = 0; kk < 4; kk++) {
            short8 af0 = *(const short8*)(w2c + kk * 32);
            short8 af1 = *(const short8*)(w2c + 8192 + kk * 32);
            int ko = kk * 32 + lgrp * 8;
            #pragma unroll
            for (int mt = 0; mt < 4; mt++) {
                short8 bf = *(const short8*)(Pb + (mt * 16 + lane15) * 136 + ko);
                acc2[0][mt] = mfma16(af0, bf, acc2[0][mt]);
                acc2[1][mt] = mfma16(af1, bf, acc2[1][mt]);
            }
        }
    }

    __syncthreads();                         // all GEMM2 done; Ax free
    unsigned short* Ob = Ax;                 // [64 m][136] bf16: Out*gate
    #pragma unroll
    for (int i = 0; i < 2; i++) {
        int db = dh * 32 + i * 16 + lgrp * 4;
        #pragma unroll
        for (int mt = 0; mt < 4; mt++) {
            int m = mt * 16 + lane15;
            float gm = gats[m];
            floatx4 v = acc2[i][mt];
            uintx2 o; o[0] = pk2bf(v[0] * gm, v[1] * gm); o[1] = pk2bf(v[2] * gm, v[3] * gm);
            *(uintx2*)(Ob + m * 136 + db) = o;
        }
    }
    __syncthreads();                         // Ob ready

    // GEMM3: H^T; A = Wh1T rows (global), B = Ob (LDS)
    floatx4 acc3[4];
    #pragma unroll
    for (int j = 0; j < 4; j++) acc3[j] = (floatx4){0.f, 0.f, 0.f, 0.f};
    #pragma unroll
    for (int kk = 0; kk < 4; kk++) {
        short8 af = *(const short8*)(w3p + kk * 32);
        int ko = kk * 32 + lgrp * 8;
        #pragma unroll
        for (int mt = 0; mt < 4; mt++) {
            short8 bf = *(const short8*)(Ob + (mt * 16 + lane15) * 136 + ko);
            acc3[mt] = mfma16(af, bf, acc3[mt]);
        }
    }
    float* H = (float*)Pb;                   // [64 m][68] f32
    int hb = dh * 16 + lgrp * 4;
    floatx4 b4 = *(const floatx4*)(bh1l + hb);
    #pragma unroll
    for (int mt = 0; mt < 4; mt++) {
        int m = mt * 16 + lane15;
        floatx4 v = acc3[mt] + b4;
        floatx4 hv;
        hv[0] = fmaxf(v[0], 0.f); hv[1] = fmaxf(v[1], 0.f);
        hv[2] = fmaxf(v[2], 0.f); hv[3] = fmaxf(v[3], 0.f);
        *(floatx4*)(H + m * 68 + hb) = hv;
    }
    __syncthreads();                         // H complete

    int mloc = tid >> 2, c0 = (tid & 3) * 2;
    int tk = toks[mloc];
    float z0 = bh2l[c0], z1 = bh2l[c0 + 1];
    const floatx4* Hr4 = (const floatx4*)(H + mloc * 68);
    #pragma unroll
    for (int h4 = 0; h4 < 16; h4++) {
        floatx4 hv = Hr4[h4];
        #pragma unroll
        for (int r = 0; r < 4; r++) {
            int h = h4 * 4 + r;
            z0 += hv[r] * Wh2l[h * 8 + c0];
            z1 += hv[r] * Wh2l[h * 8 + c0 + 1];
        }
    }
    if (tk >= 0) {
        float2 rr;
        rr.x = __builtin_amdgcn_rcpf(1.0f + __expf(-z0));
        rr.y = __builtin_amdgcn_rcpf(1.0f + __expf(-z1));
        *(float2*)(result + (long)tk * 8 + c0) = rr;
    }
}

// ---------------- launch ----------------

extern "C" void kernel_launch(void* const* d_in, const int* in_sizes, int n_in,
                              void* d_out, int out_size, void* d_ws, size_t ws_size,
                              hipStream_t stream) {
    const int* op_idx = (const int*)d_in[0];
    const int* a_in   = (const int*)d_in[1];
    const int* b_in_i = (const int*)d_in[2];
    const int* c_in   = (const int*)d_in[3];
    const float* op_embed = (const float*)d_in[4];
    const float* W_in  = (const float*)d_in[5];
    const float* b_in  = (const float*)d_in[6];
    const float* Wr    = (const float*)d_in[7];
    const float* W1    = (const float*)d_in[8];
    const float* W2    = (const float*)d_in[9];
    const float* Wh1   = (const float*)d_in[10];
    const float* bh1   = (const float*)d_in[11];
    const float* Wh2   = (const float*)d_in[12];
    const float* bh2   = (const float*)d_in[13];

    const long B = in_sizes[0];  // 262144
    float* result = (float*)d_out;
    float* d_idx  = (float*)d_out + B * 8;
    float* d_aux  = (float*)d_out + B * 9;

    unsigned char* ws = (unsigned char*)d_ws;
    unsigned short* xq   = (unsigned short*)(ws + 0);               // 2*B*128
    unsigned short* W1qT = (unsigned short*)(ws + 67108864);
    unsigned short* W2qT = (unsigned short*)(ws + 69206016);
    unsigned short* Wh1T = (unsigned short*)(ws + 71303168);
    float* gate  = (float*)(ws + 71319552);
    int*   bucket= (int*)  (ws + 72368128);
    float* Ta    = (float*)(ws + 73416704);
    float* Tb    = (float*)(ws + 73547776);
    float* embW  = (float*)(ws + 73678848);
    float* Tc    = (float*)(ws + 73682944);
    float* TaR   = (float*)(ws + 73683456);
    float* TbR   = (float*)(ws + 73699840);
    float* embWr = (float*)(ws + 73716224);
    float* TcR   = (float*)(ws + 73716736);
    unsigned char* acc = ws + 73716800;
    float* s1sum   = (float*)(acc + 0);
    float* s2sum   = (float*)(acc + 64);
    float* ternsum = (float*)(acc + 128);
    float* psum    = (float*)(acc + 192);
    int*   cnt     = (int*)(acc + 256);
    int*   fill    = (int*)(acc + 320);
    int*   offsets = (int*)(acc + 384);
    int*   chunkpre= (int*)(acc + 452);

    hipMemsetAsync(acc, 0, 576, stream);

    k_sumabs<<<32, 256, 0, stream>>>(W1, W2, s1sum, s2sum);
    k_quant<<<512, 256, 0, stream>>>(W1, W2, s1sum, s2sum, W1qT, W2qT, ternsum);
    k_tables<<<293, 256, 0, stream>>>(op_embed, W_in, b_in, Wh1, embW, Ta, Tb, Tc, Wh1T);
    k_tablesR<<<33, 256, 0, stream>>>(embW, Ta, Tb, Tc, Wr, embWr, TaR, TbR, TcR);
    k_front<<<1024, 256, 0, stream>>>(op_idx, a_in, b_in_i, c_in,
                                      embW, Ta, Tb, Tc, embWr, TaR, TbR, TcR,
                                      xq, gate, psum, cnt, d_idx);
    k_prefix_aux<<<1, 64, 0, stream>>>(cnt, psum, ternsum, offsets, chunkpre, d_aux, (float)B);
    k_scatter<<<(int)(B / 256), 256, 0, stream>>>(d_idx, offsets, fill, bucket);
    k_ffn<<<4112, 256, 37664, stream>>>(xq, gate, bucket, cnt, offsets, chunkpre,
                                        W1qT, W2qT, Wh1T, Wh2, bh1, bh2, result);
}

// Round 5
// 287.797 us; speedup vs baseline: 2.7717x; 1.3269x over previous
//
#include <hip/hip_runtime.h>
#include <hip/hip_bf16.h>
#include <math.h>

typedef __attribute__((ext_vector_type(8))) short short8;
typedef __attribute__((ext_vector_type(4))) float floatx4;
typedef __attribute__((ext_vector_type(4))) unsigned int uintx4;
typedef __attribute__((ext_vector_type(2))) unsigned int uintx2;

__device__ __forceinline__ unsigned short f2bf(float f) {
    unsigned int u = __float_as_uint(f);
    unsigned int r = (u + 0x7fffu + ((u >> 16) & 1u)) >> 16;
    return (unsigned short)r;
}

__device__ __forceinline__ unsigned int pk2bf(float a, float b) {
    unsigned int ua = __float_as_uint(a);
    ua = ua + 0x7fffu + ((ua >> 16) & 1u);
    unsigned int ub = __float_as_uint(b);
    ub = ub + 0x7fffu + ((ub >> 16) & 1u);
    return (ua >> 16) | (ub & 0xffff0000u);
}

__device__ __forceinline__ float gelu_f(float u) {
    float u2 = u * u;
    float e = __expf(-1.5957691216f * u * (1.0f + 0.044715f * u2));
    return u * __builtin_amdgcn_rcpf(1.0f + e);
}

__device__ __forceinline__ floatx4 mfma16(short8 a, short8 b, floatx4 c) {
    return __builtin_amdgcn_mfma_f32_16x16x32_bf16(a, b, c, 0, 0, 0);
}

// ---------------- Phase A ----------------

// 512 blocks: deterministic partial |W| sums (16 partials per tile)
__global__ __launch_bounds__(256) void k_sumabs(const float* __restrict__ W1,
                                                const float* __restrict__ W2,
                                                float* __restrict__ partials) {
    int blk = blockIdx.x;
    bool isW1 = blk < 256;
    const float* W = (isW1 ? W1 : W2) + (long)(isW1 ? blk : blk - 256) * 4096;
    float s = 0.f;
    #pragma unroll
    for (int i = 0; i < 4; i++) {
        floatx4 v = *(const floatx4*)(W + i * 1024 + threadIdx.x * 4);
        s += fabsf(v[0]) + fabsf(v[1]) + fabsf(v[2]) + fabsf(v[3]);
    }
    __shared__ float red[256];
    red[threadIdx.x] = s; __syncthreads();
    for (int st = 128; st > 0; st >>= 1) {
        if (threadIdx.x < st) red[threadIdx.x] += red[threadIdx.x + st];
        __syncthreads();
    }
    if (threadIdx.x == 0) partials[blk] = red[0];
}

// 512 blocks x 256 threads x 16 elems; deterministic s from partials
__global__ __launch_bounds__(256) void k_quant(
        const float* __restrict__ W1, const float* __restrict__ W2,
        const float* __restrict__ partials,
        unsigned short* __restrict__ W1qT, unsigned short* __restrict__ W2qT,
        float* ternsum) {
    int blk = blockIdx.x;
    bool isW1 = blk < 256;
    long el0 = (long)(isW1 ? blk : blk - 256) * 4096;
    int t = (int)(el0 >> 16);
    const float* part = partials + (isW1 ? 0 : 256) + t * 16;
    float ssum = 0.f;
    #pragma unroll
    for (int i = 0; i < 16; i++) ssum += part[i];
    float s = ssum * (1.0f / 65536.0f);
    float thr = 0.7f * s;
    const float* Wsrc = (isW1 ? W1 : W2) + el0;
    unsigned short* dst = (isW1 ? W1qT : W2qT) + (long)t * 65536;
    int locbase = (int)(el0 & 65535);
    float dsum = 0.f;
    #pragma unroll
    for (int i = 0; i < 4; i++) {
        int off = i * 1024 + threadIdx.x * 4;
        floatx4 w = *(const floatx4*)(Wsrc + off);
        int loc = locbase + off;
        #pragma unroll
        for (int r = 0; r < 4; r++) {
            float wv = w[r];
            float q = (fabsf(wv) > thr) ? (wv > 0.f ? s : -s) : 0.f;
            dsum += fabsf(wv - q);
            int lr = loc + r;
            int addr = isW1 ? ((lr & 511) * 128 + (lr >> 9))
                            : ((lr & 127) * 512 + (lr >> 7));
            dst[addr] = f2bf(q);
        }
    }
    __shared__ float red[256];
    red[threadIdx.x] = dsum; __syncthreads();
    for (int st2 = 128; st2 > 0; st2 >>= 1) {
        if (threadIdx.x < st2) red[threadIdx.x] += red[threadIdx.x + st2];
        __syncthreads();
    }
    if (threadIdx.x == 0) atomicAdd(ternsum, red[0]);
}

// W23qT[t][h][k2] = (W2q[t] @ Wh1)^T, bf16
__global__ __launch_bounds__(256) void k_w23(
        const unsigned short* __restrict__ W2qT, const float* __restrict__ Wh1,
        unsigned short* __restrict__ W23qT) {
    int t = blockIdx.x >> 6, h = blockIdx.x & 63;
    __shared__ float wcol[128];
    if (threadIdx.x < 128) wcol[threadIdx.x] = Wh1[threadIdx.x * 64 + h];
    __syncthreads();
    int k2 = threadIdx.x * 2;
    const unsigned short* w2 = W2qT + (long)t * 65536 + k2;
    float a0 = 0.f, a1 = 0.f;
    #pragma unroll 8
    for (int d = 0; d < 128; d++) {
        unsigned int u = *(const unsigned int*)(w2 + d * 512);
        float w = wcol[d];
        a0 += w * __uint_as_float(u << 16);
        a1 += w * __uint_as_float(u & 0xffff0000u);
    }
    *(unsigned int*)(W23qT + ((long)(t * 64 + h)) * 512 + k2) = pk2bf(a0, a1);
}

__global__ void k_tables(const float* __restrict__ op_embed, const float* __restrict__ W_in,
                         const float* __restrict__ b_in,
                         float* embW, float* Ta, float* Tb, float* Tc) {
    int i = blockIdx.x * 256 + threadIdx.x;
    if (i < 1024) {
        int op = i >> 7, j = i & 127;
        float s = b_in[j];
        #pragma unroll
        for (int k = 0; k < 32; k++) s += op_embed[op * 32 + k] * W_in[k * 128 + j];
        embW[i] = s;
    } else if (i < 1024 + 32768) {
        int r = i - 1024; int a = r >> 7, j = r & 127;
        float s = 0.f;
        #pragma unroll
        for (int bit = 0; bit < 8; bit++) if ((a >> bit) & 1) s += W_in[(32 + bit) * 128 + j];
        Ta[r] = s;
    } else if (i < 33792 + 32768) {
        int r = i - 33792; int b = r >> 7, j = r & 127;
        float s = 0.f;
        #pragma unroll
        for (int bit = 0; bit < 8; bit++) if ((b >> bit) & 1) s += W_in[(40 + bit) * 128 + j];
        Tb[r] = s;
    } else if (i < 66560 + 128) {
        int j = i - 66560; Tc[j] = W_in[48 * 128 + j];
    }
}

__global__ void k_tablesR(const float* __restrict__ embW, const float* __restrict__ Ta,
                          const float* __restrict__ Tb, const float* __restrict__ Tc,
                          const float* __restrict__ Wr,
                          float* embWr, float* TaR, float* TbR, float* TcR) {
    int i = blockIdx.x * 256 + threadIdx.x;
    int row = i >> 4, t = i & 15;
    const float* src; float* dst;
    if (row < 8)        { src = embW + row * 128;        dst = embWr + i; }
    else if (row < 264) { src = Ta + (row - 8) * 128;    dst = TaR + (row - 8) * 16 + t; }
    else if (row < 520) { src = Tb + (row - 264) * 128;  dst = TbR + (row - 264) * 16 + t; }
    else if (row == 520){ src = Tc;                      dst = TcR + t; }
    else return;
    float s = 0.f;
    for (int j = 0; j < 128; j++) s += src[j] * Wr[j * 16 + t];
    *dst = s;
}

// ---------------- Phase B: router + x ----------------

__global__ __launch_bounds__(256) void k_front(
        const int* __restrict__ op_idx, const int* __restrict__ a_in,
        const int* __restrict__ b_in_i, const int* __restrict__ c_in,
        const float* __restrict__ embW, const float* __restrict__ Ta,
        const float* __restrict__ Tb, const float* __restrict__ Tc,
        const float* __restrict__ embWr, const float* __restrict__ TaR,
        const float* __restrict__ TbR, const float* __restrict__ TcR,
        unsigned short* __restrict__ xq, float* __restrict__ gate_out,
        float* psum, int* cnt, float* __restrict__ d_idx) {
    __shared__ float sp[4][16];
    __shared__ int sc[4][16];
    int gid = blockIdx.x * 256 + threadIdx.x;
    int lane = threadIdx.x & 63;
    int j = lane & 15;
    int grpbase = lane & 48;
    float psum_acc = 0.f; int cnt_acc = 0;

    #pragma unroll 1
    for (int it = 0; it < 16; it++) {
        int tok = it * 16384 + (gid >> 4);
        int op = op_idx[tok], a = a_in[tok], b = b_in_i[tok], c = c_in[tok];
        float cf = (float)c;

        float lg = embWr[op * 16 + j] + TaR[a * 16 + j] + TbR[b * 16 + j] + cf * TcR[j];
        float m = lg;
        m = fmaxf(m, __shfl_xor(m, 8, 16));
        m = fmaxf(m, __shfl_xor(m, 4, 16));
        m = fmaxf(m, __shfl_xor(m, 2, 16));
        m = fmaxf(m, __shfl_xor(m, 1, 16));
        float p = __expf(lg - m);
        float s = p;
        s += __shfl_xor(s, 8, 16);
        s += __shfl_xor(s, 4, 16);
        s += __shfl_xor(s, 2, 16);
        s += __shfl_xor(s, 1, 16);
        float g = __builtin_amdgcn_rcpf(s);
        unsigned long long ball = __ballot(lg == m);
        int bi = __ffsll((unsigned long long)((ball >> grpbase) & 0xffffULL)) - 1;
        psum_acc += p * g;
        cnt_acc += (j == bi) ? 1 : 0;
        if (j == 0) { gate_out[tok] = g; d_idx[tok] = (float)bi; }

        int d0 = j * 8;
        const floatx4* E  = (const floatx4*)(embW + op * 128 + d0);
        const floatx4* A4 = (const floatx4*)(Ta + a * 128 + d0);
        const floatx4* B4 = (const floatx4*)(Tb + b * 128 + d0);
        const floatx4* C4 = (const floatx4*)(Tc + d0);
        floatx4 v0 = E[0] + A4[0] + B4[0] + cf * C4[0];
        floatx4 v1 = E[1] + A4[1] + B4[1] + cf * C4[1];
        uintx4 o;
        o[0] = pk2bf(v0[0], v0[1]);
        o[1] = pk2bf(v0[2], v0[3]);
        o[2] = pk2bf(v1[0], v1[1]);
        o[3] = pk2bf(v1[2], v1[3]);
        *(uintx4*)(xq + (long)tok * 128 + d0) = o;
    }

    psum_acc += __shfl_xor(psum_acc, 16);
    psum_acc += __shfl_xor(psum_acc, 32);
    cnt_acc += __shfl_xor(cnt_acc, 16);
    cnt_acc += __shfl_xor(cnt_acc, 32);
    int wv = threadIdx.x >> 6;
    if (lane < 16) { sp[wv][j] = psum_acc; sc[wv][j] = cnt_acc; }
    __syncthreads();
    if (threadIdx.x < 16) {
        int jj = threadIdx.x;
        atomicAdd(&psum[jj], sp[0][jj] + sp[1][jj] + sp[2][jj] + sp[3][jj]);
        atomicAdd(&cnt[jj], sc[0][jj] + sc[1][jj] + sc[2][jj] + sc[3][jj]);
    }
}

// ---------------- scatter (local prefix from cnt) ----------------

__global__ void k_scatter(const float* __restrict__ d_idx, const int* __restrict__ cnt,
                          int* fill, int* __restrict__ bucket) {
    __shared__ int lc[16], lbase[16];
    if (threadIdx.x < 16) lc[threadIdx.x] = 0;
    __syncthreads();
    int offs[16];
    {
        int off = 0;
        #pragma unroll
        for (int tt = 0; tt < 16; tt++) { offs[tt] = off; off += cnt[tt]; }
    }
    int tok = blockIdx.x * 256 + threadIdx.x;
    int t = (int)d_idx[tok];
    int lpos = atomicAdd(&lc[t], 1);
    __syncthreads();
    if (threadIdx.x < 16) lbase[threadIdx.x] = atomicAdd(&fill[threadIdx.x], lc[threadIdx.x]);
    __syncthreads();
    bucket[offs[t] + lbase[t] + lpos] = tok;
}

// ---------------- Phase C: MoE FFN + fused head ----------------
// GEMM1: P^T = W1 @ X^T (A=W1 rows global, B=Ax LDS) -> gelu -> Pb
// GEMM2': Hpre^T = W23 @ P^T via (A=W23 rows global, B=Pb LDS), accum over chunks
// H = relu(gate*Hpre + bh1) -> head sigmoid(H@Wh2+bh2)

__global__ __launch_bounds__(256, 4) void k_ffn(
    const unsigned short* __restrict__ xq, const float* __restrict__ gate,
    const int* __restrict__ bucket, const int* __restrict__ cnt_g,
    const float* __restrict__ psum_g, const float* __restrict__ ternsum_g,
    const unsigned short* __restrict__ W1qT, const unsigned short* __restrict__ W23qT,
    const float* __restrict__ Wh2, const float* __restrict__ bh1,
    const float* __restrict__ bh2,
    float* __restrict__ result, float* __restrict__ d_aux) {

    extern __shared__ __align__(16) unsigned char smem[];
    unsigned short* Ax = (unsigned short*)smem;            // [64][136] bf16
    unsigned short* Pb = Ax + 64 * 136;                    // [64][136] bf16; later H f32 [64][68]
    int*   toks = (int*)(smem + 34816);
    float* gats = (float*)(smem + 35072);
    float* Wh2l = (float*)(smem + 35328);                  // 512 f
    float* bh2l = (float*)(smem + 37376);                  // 8 f
    float* bh1l = (float*)(smem + 37408);                  // 64 f

    int bid = blockIdx.x;
    // per-block uniform bid -> (tile, chunk) mapping from cnt
    int t = -1, ci = 0, nt = 0, base = 0;
    {
        int coff = 0, off = 0;
        #pragma unroll 1
        for (int tt = 0; tt < 16; tt++) {
            int c = cnt_g[tt];
            int ch = (c + 63) >> 6;
            if (t < 0 && bid < coff + ch) { t = tt; ci = bid - coff; nt = c; base = off + ci * 64; }
            coff += ch; off += c;
        }
    }
    if (t < 0) return;
    int nvalid = nt - ci * 64; if (nvalid > 64) nvalid = 64;

    int tid = threadIdx.x;
    if (tid < 64) {
        int tk = (tid < nvalid) ? bucket[base + tid] : -1;
        toks[tid] = tk;
        gats[tid] = (tk >= 0) ? gate[tk] : 0.0f;
    }
    Wh2l[tid] = Wh2[tid];
    Wh2l[tid + 256] = Wh2[tid + 256];
    if (tid < 8) bh2l[tid] = bh2[tid];
    else if (tid < 72) bh1l[tid - 8] = bh1[tid - 8];
    __syncthreads();

    // stage x rows (gathered, zero-padded)
    #pragma unroll
    for (int it = 0; it < 4; it++) {
        int seg = it * 256 + tid; int r = seg >> 4, sg = seg & 15;
        int tk = toks[r];
        uintx4 v = {0u, 0u, 0u, 0u};
        if (tk >= 0) v = *(const uintx4*)(xq + (long)tk * 128 + sg * 8);
        *(uintx4*)(Ax + r * 136 + sg * 8) = v;
    }
    __syncthreads();

    int lane = tid & 63, dh = tid >> 6;
    int lane15 = lane & 15, lgrp = lane >> 4;

    floatx4 acc3[4];
    #pragma unroll
    for (int j = 0; j < 4; j++) acc3[j] = (floatx4){0.f, 0.f, 0.f, 0.f};

    const unsigned short* w1p = W1qT + (long)t * 65536 + (dh * 32 + lane15) * 128 + lgrp * 8;
    const unsigned short* w23p = W23qT + ((long)t * 64 + dh * 16 + lane15) * 512 + lgrp * 8;

    for (int nc = 0; nc < 4; nc++) {
        // GEMM1: A = W1 rows (global), B = Ax (LDS)
        floatx4 acc1[2][4];
        #pragma unroll
        for (int i = 0; i < 2; i++)
            #pragma unroll
            for (int j = 0; j < 4; j++) acc1[i][j] = (floatx4){0.f, 0.f, 0.f, 0.f};

        const unsigned short* w1c = w1p + nc * 16384;
        #pragma unroll
        for (int kk = 0; kk < 4; kk++) {
            short8 af0 = *(const short8*)(w1c + kk * 32);
            short8 af1 = *(const short8*)(w1c + 2048 + kk * 32);
            int ko = kk * 32 + lgrp * 8;
            #pragma unroll
            for (int mt = 0; mt < 4; mt++) {
                short8 bf = *(const short8*)(Ax + (mt * 16 + lane15) * 136 + ko);
                acc1[0][mt] = mfma16(af0, bf, acc1[0][mt]);
                acc1[1][mt] = mfma16(af1, bf, acc1[1][mt]);
            }
        }
        __syncthreads();                     // prev GEMM2' Pb reads done

        // gelu -> Pb[m][k2local]
        #pragma unroll
        for (int i = 0; i < 2; i++) {
            int k2b = dh * 32 + i * 16 + lgrp * 4;
            #pragma unroll
            for (int mt = 0; mt < 4; mt++) {
                int m = mt * 16 + lane15;
                floatx4 v = acc1[i][mt];
                float g0 = gelu_f(v[0]), g1v = gelu_f(v[1]);
                float g2v = gelu_f(v[2]), g3 = gelu_f(v[3]);
                uintx2 o; o[0] = pk2bf(g0, g1v); o[1] = pk2bf(g2v, g3);
                *(uintx2*)(Pb + m * 136 + k2b) = o;
            }
        }
        __syncthreads();                     // Pb ready

        // GEMM2': A = W23 rows (global), B = Pb (LDS), accum
        const unsigned short* w23c = w23p + nc * 128;
        #pragma unroll
        for (int kk = 0; kk < 4; kk++) {
            short8 af = *(const short8*)(w23c + kk * 32);
            int ko = kk * 32 + lgrp * 8;
            #pragma unroll
            for (int mt = 0; mt < 4; mt++) {
                short8 bf = *(const short8*)(Pb + (mt * 16 + lane15) * 136 + ko);
                acc3[mt] = mfma16(af, bf, acc3[mt]);
            }
        }
    }

    __syncthreads();                         // last GEMM2' reads done; Pb free
    float* H = (float*)Pb;                   // [64 m][68] f32
    int hb = dh * 16 + lgrp * 4;
    floatx4 b4 = *(const floatx4*)(bh1l + hb);
    #pragma unroll
    for (int mt = 0; mt < 4; mt++) {
        int m = mt * 16 + lane15;
        float gm = gats[m];
        floatx4 v;
        v[0] = fmaxf(acc3[mt][0] * gm + b4[0], 0.f);
        v[1] = fmaxf(acc3[mt][1] * gm + b4[1], 0.f);
        v[2] = fmaxf(acc3[mt][2] * gm + b4[2], 0.f);
        v[3] = fmaxf(acc3[mt][3] * gm + b4[3], 0.f);
        *(floatx4*)(H + m * 68 + hb) = v;
    }
    __syncthreads();                         // H complete

    int mloc = tid >> 2, c0 = (tid & 3) * 2;
    int tk = toks[mloc];
    float z0 = bh2l[c0], z1 = bh2l[c0 + 1];
    const floatx4* Hr4 = (const floatx4*)(H + mloc * 68);
    #pragma unroll
    for (int h4 = 0; h4 < 16; h4++) {
        floatx4 hv = Hr4[h4];
        #pragma unroll
        for (int r = 0; r < 4; r++) {
            int h = h4 * 4 + r;
            z0 += hv[r] * Wh2l[h * 8 + c0];
            z1 += hv[r] * Wh2l[h * 8 + c0 + 1];
        }
    }
    if (tk >= 0) {
        float2 rr;
        rr.x = __builtin_amdgcn_rcpf(1.0f + __expf(-z0));
        rr.y = __builtin_amdgcn_rcpf(1.0f + __expf(-z1));
        *(float2*)(result + (long)tk * 8 + c0) = rr;
    }

    // aux loss (block 0 only)
    if (bid == 0 && tid == 0) {
        const float Bf = 262144.0f;
        float tern = ternsum_g[0] * (1.0f / 1048576.0f);
        float sp = 0.f; float cp[4] = {0.f, 0.f, 0.f, 0.f};
        for (int tt = 0; tt < 16; tt++) {
            float frac = (float)cnt_g[tt] / Bf, mp = psum_g[tt] / Bf;
            sp += frac * mp; cp[tt >> 2] += mp;
        }
        float dv = 0.f;
        for (int cc = 0; cc < 4; cc++) dv += cp[cc] * logf(cp[cc] + 1e-9f);
        d_aux[0] = 0.01f * tern + 0.005f * (16.0f * sp) + 0.01f * dv;
    }
}

// ---------------- launch ----------------

extern "C" void kernel_launch(void* const* d_in, const int* in_sizes, int n_in,
                              void* d_out, int out_size, void* d_ws, size_t ws_size,
                              hipStream_t stream) {
    const int* op_idx = (const int*)d_in[0];
    const int* a_in   = (const int*)d_in[1];
    const int* b_in_i = (const int*)d_in[2];
    const int* c_in   = (const int*)d_in[3];
    const float* op_embed = (const float*)d_in[4];
    const float* W_in  = (const float*)d_in[5];
    const float* b_in  = (const float*)d_in[6];
    const float* Wr    = (const float*)d_in[7];
    const float* W1    = (const float*)d_in[8];
    const float* W2    = (const float*)d_in[9];
    const float* Wh1   = (const float*)d_in[10];
    const float* bh1   = (const float*)d_in[11];
    const float* Wh2   = (const float*)d_in[12];
    const float* bh2   = (const float*)d_in[13];

    const long B = in_sizes[0];  // 262144
    float* result = (float*)d_out;
    float* d_idx  = (float*)d_out + B * 8;
    float* d_aux  = (float*)d_out + B * 9;

    unsigned char* ws = (unsigned char*)d_ws;
    unsigned short* xq    = (unsigned short*)(ws + 0);            // 64 MB
    unsigned short* W1qT  = (unsigned short*)(ws + 67108864);     // 2 MB
    unsigned short* W2qT  = (unsigned short*)(ws + 69206016);     // 2 MB
    unsigned short* W23qT = (unsigned short*)(ws + 71303168);     // 1 MB
    float* gate  = (float*)(ws + 72351744);                       // 1 MB
    int*   bucket= (int*)  (ws + 73400320);                       // 1 MB
    float* Ta    = (float*)(ws + 74448896);                       // 128 KB
    float* Tb    = (float*)(ws + 74579968);                       // 128 KB
    float* embW  = (float*)(ws + 74711040);                       // 4 KB
    float* Tc    = (float*)(ws + 74715136);                       // 512 B
    float* TaR   = (float*)(ws + 74715648);                       // 16 KB
    float* TbR   = (float*)(ws + 74732032);                       // 16 KB
    float* embWr = (float*)(ws + 74748416);                       // 512 B
    float* TcR   = (float*)(ws + 74748928);                       // 64 B
    float* partials = (float*)(ws + 74748992);                    // 2 KB
    unsigned char* acc = ws + 74751040;
    float* ternsum = (float*)(acc + 0);
    float* psum    = (float*)(acc + 64);
    int*   cnt     = (int*)(acc + 128);
    int*   fill    = (int*)(acc + 192);

    hipMemsetAsync(acc, 0, 256, stream);

    k_sumabs<<<512, 256, 0, stream>>>(W1, W2, partials);
    k_quant<<<512, 256, 0, stream>>>(W1, W2, partials, W1qT, W2qT, ternsum);
    k_tables<<<261, 256, 0, stream>>>(op_embed, W_in, b_in, embW, Ta, Tb, Tc);
    k_tablesR<<<33, 256, 0, stream>>>(embW, Ta, Tb, Tc, Wr, embWr, TaR, TbR, TcR);
    k_front<<<1024, 256, 0, stream>>>(op_idx, a_in, b_in_i, c_in,
                                      embW, Ta, Tb, Tc, embWr, TaR, TbR, TcR,
                                      xq, gate, psum, cnt, d_idx);
    k_w23<<<1024, 256, 0, stream>>>(W2qT, Wh1, W23qT);
    k_scatter<<<(int)(B / 256), 256, 0, stream>>>(d_idx, cnt, fill, bucket);
    k_ffn<<<4112, 256, 37664, stream>>>(xq, gate, bucket, cnt, psum, ternsum,
                                        W1qT, W23qT, Wh2, bh1, bh2, result, d_aux);
}